// Round 8
// baseline (982.406 us; speedup 1.0000x reference)
//
#include <hip/hip_runtime.h>
#include <hip/hip_bf16.h>
#include <math.h>

#define N 4
#define C 256
#define H 128
#define W 128
#define CO 288        // GROUP * K * K = 32 * 9
#define OH 126
#define OW 126
#define GROUP 32
#define CPG 8
#define EPS 1e-5f

#define HW (OH*OW)          // 15876
#define XSLICE (H*W)        // 16384
#define XNSTRIDE (C*H*W)    // 4194304
#define SNSTRIDE (CO*HW)    // 4572288
#define LONSTRIDE (C*HW)    // 4064256
#define WSTRIDE (CO*256)    // 73728 u16 per shift s
#define WTOT (9*CO*256)     // 663552 u16 per table (wlT = whT + WTOT)
#define XTOT (N*H*W*C)      // 16777216 u16 per table (xl = xh + XTOT)

typedef unsigned short u16;
typedef __attribute__((ext_vector_type(8))) short short8;
typedef __attribute__((ext_vector_type(4))) float float4v;

__device__ inline u16 f2bf(float v) {
    __hip_bfloat16 b = __float2bfloat16(v);
    return __builtin_bit_cast(u16, b);
}
__device__ inline float bf2f(u16 u) {
    __hip_bfloat16 b = __builtin_bit_cast(__hip_bfloat16, u);
    return __bfloat162float(b);
}

// ---------------- Prep: split x into bf16 hi/lo, transpose to NHWC ----------------
// xh/xl layout: [n][h][w][ci] (ci contiguous); xl MUST be at xh + XTOT.
__global__ __launch_bounds__(256) void split_x_kernel(const float* __restrict__ x,
                                                      u16* __restrict__ xh,
                                                      u16* __restrict__ xl) {
    const int ci = threadIdx.x;          // 0..255
    const int w0 = blockIdx.x * 8;       // 16 groups
    const int h  = blockIdx.y;
    const int n  = blockIdx.z;
    const float* src = x + ((size_t)(n*C + ci)*H + h)*W + w0;
    float4 v0 = *(const float4*)src;
    float4 v1 = *(const float4*)(src + 4);
    float vals[8] = {v0.x, v0.y, v0.z, v0.w, v1.x, v1.y, v1.z, v1.w};
    size_t obase = ((size_t)(n*H + h)*W + w0)*C + ci;
    #pragma unroll
    for (int dw = 0; dw < 8; ++dw) {
        float v = vals[dw];
        u16 hb = f2bf(v);
        xh[obase + (size_t)dw*C] = hb;
        xl[obase + (size_t)dw*C] = f2bf(v - bf2f(hb));
    }
}

// ---------------- Prep: split w into bf16 hi/lo, layout [s][co][ci] ----------------
__global__ __launch_bounds__(256) void split_w_kernel(const float* __restrict__ wgt,
                                                      u16* __restrict__ whT,
                                                      u16* __restrict__ wlT) {
    const int i = blockIdx.x*256 + threadIdx.x;  // < 9*288*256 = 663552
    const int ci = i & 255;
    const int co = (i >> 8) % CO;
    const int s  = i / (CO*256);
    float v = wgt[(size_t)co*(C*9) + (size_t)ci*9 + s];
    u16 hb = f2bf(v);
    whT[i] = hb;
    wlT[i] = f2bf(v - bf2f(hb));
}

// ---------------- Conv 3x3 VALID via bf16 MFMA implicit GEMM ----------------
// Grid (4, 63, N) = 1008 blocks, block 256 = 4 waves.
// Block: 2 output rows x 32 positions x 288 co.  Wave = 1 row x 32 pos x 144 co,
// acc[2 mt][9 j] float4 = 72 VGPR -> 4 waves/SIMD.
//
// Round-8 change (post-mortem of r7): r7's 504-block grid capped the CU at
// 2 blocks / 8 waves; the 18 per-shift B loads' L2 latency could not be hidden
// by 2 in-phase waves per SIMD (13.3k cyc/phase vs 4.2k MFMA -> MfmaUtil 27%).
// Halving the x-tile doubles the grid: 4 blocks/CU x 4 waves = 16 waves/CU at
// INDEPENDENT phases (free-running, no inter-block sync) -> latency hides via
// TLP. Per-CU L2 B-traffic <= 288 KB/phase = 2.2k cyc < 4.2k cyc MFMA.
//
// B (weights) stay global/L2-resident (2.6 MB): per-lane 16B loads, 16 x 64B
// cache lines per instruction, duplicates served by L1.
// xs (activations) in LDS, double-buffered (2 x 17408 B): next-ci0 loads issue
// at the top of the current ci0 iteration, drain at the per-ci0 barrier after
// aging through 9 shifts of compute. 8 barriers per block.
// FP accumulation order per acc[mt][j] unchanged from r4-r7 (sequential s;
// ah*bh, al*bh, ah*bl within a shift) -> sigma bitwise-identical.
__global__ __launch_bounds__(256, 4) void conv_mfma_kernel(const u16* __restrict__ xh,
                                                           const u16* __restrict__ whT,
                                                           float* __restrict__ sigma) {
    // xs chunk c = spq*136 + row*34 + col (spq = sp*4+q, row 0..3, col 0..33)
    // u16 index = buf*8704 + c*8
    __shared__ __align__(16) u16 xs[2*8*4*34*8];     // 34816 B -> 4 blocks/CU

    const int tid  = threadIdx.x;
    const int wave = tid >> 6;
    const int lane = tid & 63;
    const int m16  = lane & 15;
    const int q    = lane >> 4;
    const int wr   = wave & 1;      // output row within block
    const int wc   = wave >> 1;     // co half (144 each)
    const int ow0  = blockIdx.x * 32;
    const int oh0  = blockIdx.y * 2;
    const int n    = blockIdx.z;

    // ---- x staging: 1088 chunks; issue idx = 4t+wave, t<5, idx<17 ----
    int xoff[5];
    #pragma unroll
    for (int t = 0; t < 5; ++t) {
        int c = (4*t + wave)*64 + lane;
        if (c > 1087) c = 1087;                  // unused (guarded at issue)
        const int spq = c / 136;
        const int rem = c - spq*136;
        const int row = rem / 34;
        const int col = rem - row*34;
        int gc = ow0 + col; if (gc > W-1) gc = W-1;   // clamp feeds discarded outputs
        xoff[t] = (spq >> 2)*XTOT + ((n*H + oh0 + row)*W + gc)*C + (spq & 3)*8;
    }

    // ---- A fragment read offset (u16 units, within one buffer) ----
    const int aoff = (q*136 + wr*34 + m16)*8;    // + ky*272 + kx*8 + mt*128 ; lo +4352

    // ---- B global base: per-lane pointer into whT[s][co][ci] ----
    // tile j: co = wc*144 + j*16 + m16, k = ci0 + q*8..+8  -> 16B load
    const u16* wg = whT + (size_t)((wc*144 + m16)*256 + q*8);

    float4v acc[2][9];
    #pragma unroll
    for (int mt = 0; mt < 2; ++mt)
        #pragma unroll
        for (int j = 0; j < 9; ++j) acc[mt][j] = (float4v)(0.f);

    // ---- prologue: stage xs(ci0=0) into buf 0, drain ----
    #pragma unroll
    for (int t = 0; t < 5; ++t)
        if (t < 4 || wave == 0)
            __builtin_amdgcn_global_load_lds((const uint*)(xh + xoff[t]),
                                             (uint*)(xs + (4*t + wave)*512), 16, 0, 0);
    __syncthreads();

    int buf = 0;
    for (int ci0 = 0; ci0 < C; ci0 += 32) {
        // issue next-ci0 x loads into buf^1 now; they drain at this
        // iteration's ending barrier after aging through 9 shifts of compute
        const int nci = ci0 + 32;
        if (nci < C) {
            #pragma unroll
            for (int t = 0; t < 5; ++t)
                if (t < 4 || wave == 0)
                    __builtin_amdgcn_global_load_lds(
                        (const uint*)(xh + xoff[t] + nci),
                        (uint*)(xs + (buf^1)*8704 + (4*t + wave)*512), 16, 0, 0);
        }

        #pragma unroll 1
        for (int s = 0; s < 9; ++s) {
            const int ky = s / 3;
            const int kx = s - 3*ky;
            const u16* wp = wg + (size_t)s*WSTRIDE + ci0;

            const int ab = buf*8704 + aoff + ky*272 + kx*8;
            short8 ah0 = *(const short8*)&xs[ab];
            short8 ah1 = *(const short8*)&xs[ab + 128];
            short8 al0 = *(const short8*)&xs[ab + 4352];
            short8 al1 = *(const short8*)&xs[ab + 4352 + 128];
            __builtin_amdgcn_s_setprio(1);
            #pragma unroll
            for (int j = 0; j < 9; ++j) {
                short8 bh = *(const short8*)(wp + j*4096);
                short8 bl = *(const short8*)(wp + WTOT + j*4096);
                acc[0][j] = __builtin_amdgcn_mfma_f32_16x16x32_bf16(ah0, bh, acc[0][j], 0, 0, 0);
                acc[1][j] = __builtin_amdgcn_mfma_f32_16x16x32_bf16(ah1, bh, acc[1][j], 0, 0, 0);
                acc[0][j] = __builtin_amdgcn_mfma_f32_16x16x32_bf16(al0, bh, acc[0][j], 0, 0, 0);
                acc[1][j] = __builtin_amdgcn_mfma_f32_16x16x32_bf16(al1, bh, acc[1][j], 0, 0, 0);
                acc[0][j] = __builtin_amdgcn_mfma_f32_16x16x32_bf16(ah0, bl, acc[0][j], 0, 0, 0);
                acc[1][j] = __builtin_amdgcn_mfma_f32_16x16x32_bf16(ah1, bl, acc[1][j], 0, 0, 0);
            }
            __builtin_amdgcn_s_setprio(0);
        }

        __syncthreads();   // buf readers done + buf^1 loads drained (aged 9 shifts)
        buf ^= 1;
    }

    // store: D[row=q*4+r][col=m16]; pos = mt*16+q*4+r, co = wc*144+j*16+m16
    #pragma unroll
    for (int mt = 0; mt < 2; ++mt) {
        const int posb = mt*16 + q*4;
        #pragma unroll
        for (int j = 0; j < 9; ++j) {
            const int co = wc*144 + j*16 + m16;
            float* dst = sigma + (size_t)n*SNSTRIDE + (size_t)co*HW + (oh0 + wr)*OW;
            #pragma unroll
            for (int r = 0; r < 4; ++r) {
                const int ow = ow0 + posb + r;
                if (ow < OW) dst[ow] = acc[mt][j][r];
            }
        }
    }
}

// ---------------- Per-channel mean/var over (N, OH, OW) ----------------
__global__ __launch_bounds__(1024) void stats_kernel(const float* __restrict__ sigma,
                                                     const float* __restrict__ gamma,
                                                     const float* __restrict__ beta,
                                                     float* __restrict__ coef) {
    const int c = blockIdx.x;
    float sum = 0.f, sq = 0.f;
    for (int n = 0; n < N; ++n) {
        const float* sp = sigma + (size_t)n*SNSTRIDE + (size_t)c*HW;
        for (int i = threadIdx.x; i < HW; i += 1024) {
            float v = sp[i];
            sum += v; sq += v * v;
        }
    }
    for (int off = 32; off > 0; off >>= 1) {
        sum += __shfl_down(sum, off, 64);
        sq  += __shfl_down(sq,  off, 64);
    }
    __shared__ float ls[16], lq[16];
    const int wid = threadIdx.x >> 6, lane = threadIdx.x & 63;
    if (lane == 0) { ls[wid] = sum; lq[wid] = sq; }
    __syncthreads();
    if (threadIdx.x == 0) {
        float S = 0.f, Q = 0.f;
        #pragma unroll
        for (int i = 0; i < 16; ++i) { S += ls[i]; Q += lq[i]; }
        const float cnt = (float)(N * HW);
        float mean = S / cnt;
        float var  = Q / cnt - mean * mean;
        float a = gamma[c] * rsqrtf(var + EPS);
        coef[c]      = a;
        coef[CO + c] = beta[c] - mean * a;
    }
}

// ---------------- Fused normalize + softmax(288) + grouped dynamic 3x3 ----------------
// Single pass: no max-subtraction (normalized s -> |s| small, exp is fp32-safe),
// divide deferred: outlo holds sum_p x*e, per-position sum(e) stored in sums[];
// upsample divides each tap. One sigma sweep instead of three.
__global__ __launch_bounds__(256) void fuse_kernel(const float* __restrict__ x,
                                                   const float* __restrict__ sigma,
                                                   const float* __restrict__ coef,
                                                   float* __restrict__ outlo,
                                                   float* __restrict__ sums) {
    __shared__ float a[CO], b[CO];
    for (int i = threadIdx.x; i < CO; i += 256) {
        a[i] = coef[i];
        b[i] = coef[CO + i];
    }
    __syncthreads();

    const int gpos = blockIdx.x * 256 + threadIdx.x;
    if (gpos >= N * HW) return;
    const int n  = gpos / HW;
    const int hw = gpos - n * HW;
    const int oh = hw / OW;
    const int ow = hw - oh * OW;

    const float* sp = sigma + (size_t)n * SNSTRIDE + hw;
    const float* xb = x + (size_t)n * XNSTRIDE + oh * W + ow;
    float* ob = outlo + (size_t)n * LONSTRIDE + hw;

    float sum = 0.f;
    for (int g = 0; g < GROUP; ++g) {
        float acc[CPG];
        #pragma unroll
        for (int c = 0; c < CPG; ++c) acc[c] = 0.f;
        #pragma unroll
        for (int p = 0; p < 9; ++p) {
            const int ch = g * 9 + p;
            float s = sp[(size_t)ch * HW] * a[ch] + b[ch];
            float e = __expf(s);
            sum += e;
            const float* xr = xb + (size_t)(g * CPG) * XSLICE + (p / 3) * W + (p % 3);
            #pragma unroll
            for (int c = 0; c < CPG; ++c)
                acc[c] += xr[(size_t)c * XSLICE] * e;
        }
        #pragma unroll
        for (int c = 0; c < CPG; ++c)
            ob[(size_t)(g * CPG + c) * HW] = acc[c];
    }
    sums[gpos] = sum;
}

// ---------------- Bilinear align-corners upsample 126 -> 128 (+ softmax divide) ----
__global__ __launch_bounds__(256) void upsample_kernel(const float* __restrict__ lo,
                                                       const float* __restrict__ sums,
                                                       float* __restrict__ out) {
    const int idx = blockIdx.x * 256 + threadIdx.x;
    const int xi = idx & (W - 1);
    const int yi = (idx >> 7) & (H - 1);
    const int nc = idx >> 14;
    const int n  = nc >> 8;              // C = 256

    const float scale = 125.0f / 127.0f;
    const float sy = yi * scale;
    const float sx = xi * scale;
    int y0 = (int)sy;
    int x0 = (int)sx;
    float wy = sy - (float)y0;
    float wx = sx - (float)x0;
    int y1 = min(y0 + 1, OH - 1);
    int x1 = min(x0 + 1, OW - 1);

    const float* p  = lo + (size_t)nc * HW;
    const float* ps = sums + (size_t)n * HW;
    float v00 = p[y0 * OW + x0] / ps[y0 * OW + x0];
    float v01 = p[y0 * OW + x1] / ps[y0 * OW + x1];
    float v10 = p[y1 * OW + x0] / ps[y1 * OW + x0];
    float v11 = p[y1 * OW + x1] / ps[y1 * OW + x1];
    float top = v00 * (1.f - wx) + v01 * wx;
    float bot = v10 * (1.f - wx) + v11 * wx;
    out[idx] = top * (1.f - wy) + bot * wy;
}

extern "C" void kernel_launch(void* const* d_in, const int* in_sizes, int n_in,
                              void* d_out, int out_size, void* d_ws, size_t ws_size,
                              hipStream_t stream) {
    const float* x      = (const float*)d_in[0];
    const float* conv_w = (const float*)d_in[1];
    const float* gamma  = (const float*)d_in[2];
    const float* beta   = (const float*)d_in[3];
    float* out = (float*)d_out;
    float* ws  = (float*)d_ws;

    // workspace (floats):
    //   sigma : [0, 18289152)
    //   coef  : [18289152, +1024)
    //   outlo : [18290176, +16257024)   -- ALIASED with xh/xl (prep+conv finish first)
    //   sums  : aliased over whT (dead after conv, written by fuse, read by upsample)
    float* sigma = ws;
    float* coef  = ws + 18289152;
    float* outlo = ws + 18290176;
    u16* xhp = (u16*)(ws + 18290176);               // 16777216 u16 = 33.5 MB
    u16* xlp = xhp + (size_t)XTOT;                  // adjacent: xl = xh + XTOT
    u16* whT = xlp + (size_t)XTOT;                  // 663552 u16
    u16* wlT = whT + (size_t)WTOT;                  // adjacent: wl = wh + WTOT
    float* sums = (float*)whT;                      // 63504 floats, fits in w region
    // total ws usage ~143 MB

    split_x_kernel<<<dim3(16, 128, 4), 256, 0, stream>>>(x, xhp, xlp);
    split_w_kernel<<<(9*CO*256)/256, 256, 0, stream>>>(conv_w, whT, wlT);

    conv_mfma_kernel<<<dim3(4, 63, N), 256, 0, stream>>>(xhp, whT, sigma);

    stats_kernel<<<CO, 1024, 0, stream>>>(sigma, gamma, beta, coef);

    fuse_kernel<<<(N * HW + 255) / 256, 256, 0, stream>>>(x, sigma, coef, outlo, sums);

    upsample_kernel<<<(N * C * H * W) / 256, 256, 0, stream>>>(outlo, sums, out);
}

// Round 9
// 644.785 us; speedup vs baseline: 1.5236x; 1.5236x over previous
//
#include <hip/hip_runtime.h>
#include <hip/hip_bf16.h>
#include <math.h>

#define N 4
#define C 256
#define H 128
#define W 128
#define CO 288        // GROUP * K * K = 32 * 9
#define OH 126
#define OW 126
#define GROUP 32
#define CPG 8
#define EPS 1e-5f

#define HW (OH*OW)          // 15876
#define XSLICE (H*W)        // 16384
#define XNSTRIDE (C*H*W)    // 4194304
#define SNSTRIDE (CO*HW)    // 4572288
#define LONSTRIDE (C*HW)    // 4064256
#define WSTRIDE (CO*256)    // 73728 u16 per shift s
#define WTOT (9*CO*256)     // 663552 u16 per table (wlT = whT + WTOT)
#define XTOT (N*H*W*C)      // 16777216 u16 per table (xl = xh + XTOT)

typedef unsigned short u16;
typedef __attribute__((ext_vector_type(8))) short short8;
typedef __attribute__((ext_vector_type(4))) float float4v;

__device__ inline u16 f2bf(float v) {
    __hip_bfloat16 b = __float2bfloat16(v);
    return __builtin_bit_cast(u16, b);
}
__device__ inline float bf2f(u16 u) {
    __hip_bfloat16 b = __builtin_bit_cast(__hip_bfloat16, u);
    return __bfloat162float(b);
}

// ---------------- Prep: split x into bf16 hi/lo, transpose to NHWC ----------------
// xh/xl layout: [n][h][w][ci] (ci contiguous); xl MUST be at xh + XTOT.
__global__ __launch_bounds__(256) void split_x_kernel(const float* __restrict__ x,
                                                      u16* __restrict__ xh,
                                                      u16* __restrict__ xl) {
    const int ci = threadIdx.x;          // 0..255
    const int w0 = blockIdx.x * 8;       // 16 groups
    const int h  = blockIdx.y;
    const int n  = blockIdx.z;
    const float* src = x + ((size_t)(n*C + ci)*H + h)*W + w0;
    float4 v0 = *(const float4*)src;
    float4 v1 = *(const float4*)(src + 4);
    float vals[8] = {v0.x, v0.y, v0.z, v0.w, v1.x, v1.y, v1.z, v1.w};
    size_t obase = ((size_t)(n*H + h)*W + w0)*C + ci;
    #pragma unroll
    for (int dw = 0; dw < 8; ++dw) {
        float v = vals[dw];
        u16 hb = f2bf(v);
        xh[obase + (size_t)dw*C] = hb;
        xl[obase + (size_t)dw*C] = f2bf(v - bf2f(hb));
    }
}

// ---------------- Prep: split w into bf16 hi/lo, layout [s][co][ci] ----------------
__global__ __launch_bounds__(256) void split_w_kernel(const float* __restrict__ wgt,
                                                      u16* __restrict__ whT,
                                                      u16* __restrict__ wlT) {
    const int i = blockIdx.x*256 + threadIdx.x;  // < 9*288*256 = 663552
    const int ci = i & 255;
    const int co = (i >> 8) % CO;
    const int s  = i / (CO*256);
    float v = wgt[(size_t)co*(C*9) + (size_t)ci*9 + s];
    u16 hb = f2bf(v);
    whT[i] = hb;
    wlT[i] = f2bf(v - bf2f(hb));
}

// ---------------- Conv 3x3 VALID via bf16 MFMA implicit GEMM ----------------
// VERBATIM the round-4 bench-verified kernel (332 us, MfmaUtil 34%):
// Grid (2, 63, N), block 256 = 4 waves.
// Block: 2 output rows x 64 positions x 288 co.  Wave = 1 row x 64 pos x 144 co,
// acc[4 mt][9 j] float4 = 144 VGPR. 26 LDS reads feed 108 MFMAs per shift.
// Pipelined units: per shift s, {unit A: 72 MFMA (bh)} + {unit B: 36 MFMA (bl)};
// wsh double-buffered (one split per buffer); every unit issues the NEXT unit's
// global_load_lds before computing, so the vmcnt(0) drain at its ending
// __syncthreads covers loads that aged a full MFMA phase. xs restage overlaps
// into unit B of s=8.
// (The r7/r8 w-from-L2 arc measured 399/673 us -- B-load L2 latency cannot be
// hidden at 2 blocks/CU, and buying occupancy via launch_bounds starves VGPRs
// and serializes loads. w-in-LDS pipelining is the proven structure.)
__global__ __launch_bounds__(256, 2) void conv_mfma_kernel(const u16* __restrict__ xh,
                                                           const u16* __restrict__ whT,
                                                           float* __restrict__ sigma) {
    // xs chunk c = spq*264 + row*66 + col (spq = sp*4+q, row 0..3, col 0..65)
    __shared__ __align__(16) u16 xs[8*4*66*8];       // 33792 B
    // wsh: 2 buffers, each chunk c = q*288 + co (one split per buffer)
    __shared__ __align__(16) u16 wsh[2*4*288*8];     // 36864 B (total 70656 -> 2 blk/CU)

    const int tid  = threadIdx.x;
    const int wave = tid >> 6;
    const int lane = tid & 63;
    const int m16  = lane & 15;
    const int q    = lane >> 4;
    const int wr   = wave & 1;      // output row within block
    const int wc   = wave >> 1;     // co half (144 each)
    const int ow0  = blockIdx.x * 64;
    const int oh0  = blockIdx.y * 2;
    const int n    = blockIdx.z;

    // ---- w staging: 1152 chunks [q][co]; wave distribution 5/5/4/4 issues ----
    const int w_nw   = (wave < 2) ? 5 : 4;
    const int w_base = (wave < 2) ? wave*320 : 640 + (wave-2)*256;
    int wsrc[5];
    #pragma unroll
    for (int i = 0; i < 5; ++i) {
        int c = w_base + i*64 + lane;            // < 1152 by construction
        const int cq  = c / 288;
        const int cco = c - cq*288;
        wsrc[i] = cco*256 + cq*8;                // + split*WTOT + s*WSTRIDE + ci0
    }

    // ---- x staging: 2112 chunks; issue idx = 4t+wave, t<9, idx<33 ----
    int xoff[9];
    #pragma unroll
    for (int t = 0; t < 9; ++t) {
        int c = (4*t + wave)*64 + lane;
        if (c > 2111) c = 2111;                  // unused (guarded at issue)
        const int spq = c / 264;
        const int rem = c - spq*264;
        const int row = rem / 66;
        const int col = rem - row*66;
        int gc = ow0 + col; if (gc > W-1) gc = W-1;   // clamp feeds discarded outputs
        xoff[t] = (spq >> 2)*XTOT + ((n*H + oh0 + row)*W + gc)*C + (spq & 3)*8;
    }

    // ---- fragment read offsets (u16 units) ----
    const int aoff = (q*264 + wr*66 + m16)*8;    // + (ky*66+kx)*8 + mt*128 ; lo +8448
    const int boff = (q*288 + wc*144 + m16)*8;   // + buf*9216 + j*128

    float4v acc[4][9];
    #pragma unroll
    for (int mt = 0; mt < 4; ++mt)
        #pragma unroll
        for (int j = 0; j < 9; ++j) acc[mt][j] = (float4v)(0.f);

    // ---- prologue: stage xs(ci0=0) and w unit0 (s=0, hi) into buf 0 ----
    #pragma unroll
    for (int t = 0; t < 9; ++t)
        if (t < 8 || wave == 0)
            __builtin_amdgcn_global_load_lds((const uint*)(xh + xoff[t]),
                                             (uint*)(xs + (4*t + wave)*512), 16, 0, 0);
    #pragma unroll
    for (int i = 0; i < 5; ++i)
        if (i < w_nw)
            __builtin_amdgcn_global_load_lds((const uint*)(whT + wsrc[i]),
                                             (uint*)(wsh + (w_base + i*64)*8), 16, 0, 0);
    __syncthreads();

    int buf = 0;
    for (int ci0 = 0; ci0 < C; ci0 += 32) {
        #pragma unroll
        for (int ky = 0; ky < 3; ++ky)
        #pragma unroll
        for (int kx = 0; kx < 3; ++kx) {
            const int s = ky*3 + kx;

            // ======== unit A (bh): issue bl(s) into buf^1, compute 72 MFMA ========
            {
                const int soff = WTOT + s*WSTRIDE + ci0;     // lo split, same s
                #pragma unroll
                for (int i = 0; i < 5; ++i)
                    if (i < w_nw)
                        __builtin_amdgcn_global_load_lds(
                            (const uint*)(whT + soff + wsrc[i]),
                            (uint*)(wsh + ((buf^1)*1152 + w_base + i*64)*8), 16, 0, 0);
            }
            const int ab = aoff + (ky*66 + kx)*8;
            short8 ah0 = *(const short8*)&xs[ab];
            short8 ah1 = *(const short8*)&xs[ab + 128];
            short8 ah2 = *(const short8*)&xs[ab + 256];
            short8 ah3 = *(const short8*)&xs[ab + 384];
            {
                short8 al0 = *(const short8*)&xs[ab + 8448];
                short8 al1 = *(const short8*)&xs[ab + 8448 + 128];
                short8 al2 = *(const short8*)&xs[ab + 8448 + 256];
                short8 al3 = *(const short8*)&xs[ab + 8448 + 384];
                const u16* wb = wsh + buf*9216 + boff;
                __builtin_amdgcn_s_setprio(1);
                #pragma unroll
                for (int j = 0; j < 9; ++j) {
                    short8 bh = *(const short8*)&wb[j*128];
                    acc[0][j] = __builtin_amdgcn_mfma_f32_16x16x32_bf16(ah0, bh, acc[0][j], 0, 0, 0);
                    acc[1][j] = __builtin_amdgcn_mfma_f32_16x16x32_bf16(ah1, bh, acc[1][j], 0, 0, 0);
                    acc[2][j] = __builtin_amdgcn_mfma_f32_16x16x32_bf16(ah2, bh, acc[2][j], 0, 0, 0);
                    acc[3][j] = __builtin_amdgcn_mfma_f32_16x16x32_bf16(ah3, bh, acc[3][j], 0, 0, 0);
                    acc[0][j] = __builtin_amdgcn_mfma_f32_16x16x32_bf16(al0, bh, acc[0][j], 0, 0, 0);
                    acc[1][j] = __builtin_amdgcn_mfma_f32_16x16x32_bf16(al1, bh, acc[1][j], 0, 0, 0);
                    acc[2][j] = __builtin_amdgcn_mfma_f32_16x16x32_bf16(al2, bh, acc[2][j], 0, 0, 0);
                    acc[3][j] = __builtin_amdgcn_mfma_f32_16x16x32_bf16(al3, bh, acc[3][j], 0, 0, 0);
                }
                __builtin_amdgcn_s_setprio(0);
            }
            __syncthreads();     // drains bl(s) loads; bh buffer readers done
            buf ^= 1;

            // ======== unit B (bl): issue next hi into buf^1 (+xs restage at s=8) ====
            if (!(ci0 == C-32 && s == 8)) {
                int ns = s + 1, nci = ci0;
                if (ns == 9) { ns = 0; nci += 32; }
                const int soff = ns*WSTRIDE + nci;           // hi split of next unit
                #pragma unroll
                for (int i = 0; i < 5; ++i)
                    if (i < w_nw)
                        __builtin_amdgcn_global_load_lds(
                            (const uint*)(whT + soff + wsrc[i]),
                            (uint*)(wsh + ((buf^1)*1152 + w_base + i*64)*8), 16, 0, 0);
                if (s == 8) {    // xs readers finished at unit A's barrier
                    #pragma unroll
                    for (int t = 0; t < 9; ++t)
                        if (t < 8 || wave == 0)
                            __builtin_amdgcn_global_load_lds(
                                (const uint*)(xh + xoff[t] + nci),
                                (uint*)(xs + (4*t + wave)*512), 16, 0, 0);
                }
            }
            {
                const u16* wb = wsh + buf*9216 + boff;
                __builtin_amdgcn_s_setprio(1);
                #pragma unroll
                for (int j = 0; j < 9; ++j) {
                    short8 bl = *(const short8*)&wb[j*128];
                    acc[0][j] = __builtin_amdgcn_mfma_f32_16x16x32_bf16(ah0, bl, acc[0][j], 0, 0, 0);
                    acc[1][j] = __builtin_amdgcn_mfma_f32_16x16x32_bf16(ah1, bl, acc[1][j], 0, 0, 0);
                    acc[2][j] = __builtin_amdgcn_mfma_f32_16x16x32_bf16(ah2, bl, acc[2][j], 0, 0, 0);
                    acc[3][j] = __builtin_amdgcn_mfma_f32_16x16x32_bf16(ah3, bl, acc[3][j], 0, 0, 0);
                }
                __builtin_amdgcn_s_setprio(0);
            }
            __syncthreads();     // drains next-unit hi (+xs) loads; bl readers done
            buf ^= 1;
        }
    }

    // store: D[row=q*4+r][col=m16]; pos = mt*16+q*4+r, co = wc*144+j*16+m16
    #pragma unroll
    for (int mt = 0; mt < 4; ++mt) {
        const int posb = mt*16 + q*4;
        #pragma unroll
        for (int j = 0; j < 9; ++j) {
            const int co = wc*144 + j*16 + m16;
            float* dst = sigma + (size_t)n*SNSTRIDE + (size_t)co*HW + (oh0 + wr)*OW;
            #pragma unroll
            for (int r = 0; r < 4; ++r) {
                const int ow = ow0 + posb + r;
                if (ow < OW) dst[ow] = acc[mt][j][r];
            }
        }
    }
}

// ---------------- Per-channel mean/var over (N, OH, OW) ----------------
__global__ __launch_bounds__(1024) void stats_kernel(const float* __restrict__ sigma,
                                                     const float* __restrict__ gamma,
                                                     const float* __restrict__ beta,
                                                     float* __restrict__ coef) {
    const int c = blockIdx.x;
    float sum = 0.f, sq = 0.f;
    for (int n = 0; n < N; ++n) {
        const float* sp = sigma + (size_t)n*SNSTRIDE + (size_t)c*HW;
        for (int i = threadIdx.x; i < HW; i += 1024) {
            float v = sp[i];
            sum += v; sq += v * v;
        }
    }
    for (int off = 32; off > 0; off >>= 1) {
        sum += __shfl_down(sum, off, 64);
        sq  += __shfl_down(sq,  off, 64);
    }
    __shared__ float ls[16], lq[16];
    const int wid = threadIdx.x >> 6, lane = threadIdx.x & 63;
    if (lane == 0) { ls[wid] = sum; lq[wid] = sq; }
    __syncthreads();
    if (threadIdx.x == 0) {
        float S = 0.f, Q = 0.f;
        #pragma unroll
        for (int i = 0; i < 16; ++i) { S += ls[i]; Q += lq[i]; }
        const float cnt = (float)(N * HW);
        float mean = S / cnt;
        float var  = Q / cnt - mean * mean;
        float a = gamma[c] * rsqrtf(var + EPS);
        coef[c]      = a;
        coef[CO + c] = beta[c] - mean * a;
    }
}

// ---------------- Fused normalize + softmax(288) + grouped dynamic 3x3 ----------------
// Single pass: no max-subtraction (normalized s -> |s| small, exp is fp32-safe),
// divide deferred: outlo holds sum_p x*e, per-position sum(e) stored in sums[];
// upsample divides each tap. One sigma sweep instead of three.
__global__ __launch_bounds__(256) void fuse_kernel(const float* __restrict__ x,
                                                   const float* __restrict__ sigma,
                                                   const float* __restrict__ coef,
                                                   float* __restrict__ outlo,
                                                   float* __restrict__ sums) {
    __shared__ float a[CO], b[CO];
    for (int i = threadIdx.x; i < CO; i += 256) {
        a[i] = coef[i];
        b[i] = coef[CO + i];
    }
    __syncthreads();

    const int gpos = blockIdx.x * 256 + threadIdx.x;
    if (gpos >= N * HW) return;
    const int n  = gpos / HW;
    const int hw = gpos - n * HW;
    const int oh = hw / OW;
    const int ow = hw - oh * OW;

    const float* sp = sigma + (size_t)n * SNSTRIDE + hw;
    const float* xb = x + (size_t)n * XNSTRIDE + oh * W + ow;
    float* ob = outlo + (size_t)n * LONSTRIDE + hw;

    float sum = 0.f;
    for (int g = 0; g < GROUP; ++g) {
        float acc[CPG];
        #pragma unroll
        for (int c = 0; c < CPG; ++c) acc[c] = 0.f;
        #pragma unroll
        for (int p = 0; p < 9; ++p) {
            const int ch = g * 9 + p;
            float s = sp[(size_t)ch * HW] * a[ch] + b[ch];
            float e = __expf(s);
            sum += e;
            const float* xr = xb + (size_t)(g * CPG) * XSLICE + (p / 3) * W + (p % 3);
            #pragma unroll
            for (int c = 0; c < CPG; ++c)
                acc[c] += xr[(size_t)c * XSLICE] * e;
        }
        #pragma unroll
        for (int c = 0; c < CPG; ++c)
            ob[(size_t)(g * CPG + c) * HW] = acc[c];
    }
    sums[gpos] = sum;
}

// ---------------- Bilinear align-corners upsample 126 -> 128 (+ softmax divide) ----
__global__ __launch_bounds__(256) void upsample_kernel(const float* __restrict__ lo,
                                                       const float* __restrict__ sums,
                                                       float* __restrict__ out) {
    const int idx = blockIdx.x * 256 + threadIdx.x;
    const int xi = idx & (W - 1);
    const int yi = (idx >> 7) & (H - 1);
    const int nc = idx >> 14;
    const int n  = nc >> 8;              // C = 256

    const float scale = 125.0f / 127.0f;
    const float sy = yi * scale;
    const float sx = xi * scale;
    int y0 = (int)sy;
    int x0 = (int)sx;
    float wy = sy - (float)y0;
    float wx = sx - (float)x0;
    int y1 = min(y0 + 1, OH - 1);
    int x1 = min(x0 + 1, OW - 1);

    const float* p  = lo + (size_t)nc * HW;
    const float* ps = sums + (size_t)n * HW;
    float v00 = p[y0 * OW + x0] / ps[y0 * OW + x0];
    float v01 = p[y0 * OW + x1] / ps[y0 * OW + x1];
    float v10 = p[y1 * OW + x0] / ps[y1 * OW + x0];
    float v11 = p[y1 * OW + x1] / ps[y1 * OW + x1];
    float top = v00 * (1.f - wx) + v01 * wx;
    float bot = v10 * (1.f - wx) + v11 * wx;
    out[idx] = top * (1.f - wy) + bot * wy;
}

extern "C" void kernel_launch(void* const* d_in, const int* in_sizes, int n_in,
                              void* d_out, int out_size, void* d_ws, size_t ws_size,
                              hipStream_t stream) {
    const float* x      = (const float*)d_in[0];
    const float* conv_w = (const float*)d_in[1];
    const float* gamma  = (const float*)d_in[2];
    const float* beta   = (const float*)d_in[3];
    float* out = (float*)d_out;
    float* ws  = (float*)d_ws;

    // workspace (floats):
    //   sigma : [0, 18289152)
    //   coef  : [18289152, +1024)
    //   outlo : [18290176, +16257024)   -- ALIASED with xh/xl (prep+conv finish first)
    //   sums  : aliased over whT (dead after conv, written by fuse, read by upsample)
    float* sigma = ws;
    float* coef  = ws + 18289152;
    float* outlo = ws + 18290176;
    u16* xhp = (u16*)(ws + 18290176);               // 16777216 u16 = 33.5 MB
    u16* xlp = xhp + (size_t)XTOT;                  // adjacent: xl = xh + XTOT
    u16* whT = xlp + (size_t)XTOT;                  // 663552 u16
    u16* wlT = whT + (size_t)WTOT;                  // adjacent: wl = wh + WTOT
    float* sums = (float*)whT;                      // 63504 floats, fits in w region
    // total ws usage ~143 MB

    split_x_kernel<<<dim3(16, 128, 4), 256, 0, stream>>>(x, xhp, xlp);
    split_w_kernel<<<(9*CO*256)/256, 256, 0, stream>>>(conv_w, whT, wlT);

    conv_mfma_kernel<<<dim3(2, 63, N), 256, 0, stream>>>(xhp, whT, sigma);

    stats_kernel<<<CO, 1024, 0, stream>>>(sigma, gamma, beta, coef);

    fuse_kernel<<<(N * HW + 255) / 256, 256, 0, stream>>>(x, sigma, coef, outlo, sums);

    upsample_kernel<<<(N * C * H * W) / 256, 256, 0, stream>>>(outlo, sums, out);
}

// Round 10
// 614.850 us; speedup vs baseline: 1.5978x; 1.0487x over previous
//
#include <hip/hip_runtime.h>
#include <hip/hip_bf16.h>
#include <math.h>

#define N 4
#define C 256
#define H 128
#define W 128
#define CO 288        // GROUP * K * K = 32 * 9
#define OH 126
#define OW 126
#define GROUP 32
#define CPG 8
#define EPS 1e-5f

#define HW (OH*OW)          // 15876
#define XSLICE (H*W)        // 16384
#define XNSTRIDE (C*H*W)    // 4194304
#define SNSTRIDE (CO*HW)    // 4572288
#define LONSTRIDE (C*HW)    // 4064256
#define WSTRIDE (CO*256)    // 73728 u16 per shift s
#define WTOT (9*CO*256)     // 663552 u16 per table (wlT = whT + WTOT)
#define XTOT (N*H*W*C)      // 16777216 u16 per table (xl = xh + XTOT)

typedef unsigned short u16;
typedef __attribute__((ext_vector_type(8))) short short8;
typedef __attribute__((ext_vector_type(4))) float float4v;

__device__ inline u16 f2bf(float v) {
    __hip_bfloat16 b = __float2bfloat16(v);
    return __builtin_bit_cast(u16, b);
}
__device__ inline float bf2f(u16 u) {
    __hip_bfloat16 b = __builtin_bit_cast(__hip_bfloat16, u);
    return __bfloat162float(b);
}

// ---------------- Prep: split x into bf16 hi/lo, transpose to NHWC ----------------
// xh/xl layout: [n][h][w][ci] (ci contiguous); xl MUST be at xh + XTOT.
__global__ __launch_bounds__(256) void split_x_kernel(const float* __restrict__ x,
                                                      u16* __restrict__ xh,
                                                      u16* __restrict__ xl) {
    const int ci = threadIdx.x;          // 0..255
    const int w0 = blockIdx.x * 8;       // 16 groups
    const int h  = blockIdx.y;
    const int n  = blockIdx.z;
    const float* src = x + ((size_t)(n*C + ci)*H + h)*W + w0;
    float4 v0 = *(const float4*)src;
    float4 v1 = *(const float4*)(src + 4);
    float vals[8] = {v0.x, v0.y, v0.z, v0.w, v1.x, v1.y, v1.z, v1.w};
    size_t obase = ((size_t)(n*H + h)*W + w0)*C + ci;
    #pragma unroll
    for (int dw = 0; dw < 8; ++dw) {
        float v = vals[dw];
        u16 hb = f2bf(v);
        xh[obase + (size_t)dw*C] = hb;
        xl[obase + (size_t)dw*C] = f2bf(v - bf2f(hb));
    }
}

// ---------------- Prep: split w into bf16 hi/lo, layout [s][co][ci] ----------------
__global__ __launch_bounds__(256) void split_w_kernel(const float* __restrict__ wgt,
                                                      u16* __restrict__ whT,
                                                      u16* __restrict__ wlT) {
    const int i = blockIdx.x*256 + threadIdx.x;  // < 9*288*256 = 663552
    const int ci = i & 255;
    const int co = (i >> 8) % CO;
    const int s  = i / (CO*256);
    float v = wgt[(size_t)co*(C*9) + (size_t)ci*9 + s];
    u16 hb = f2bf(v);
    whT[i] = hb;
    wlT[i] = f2bf(v - bf2f(hb));
}

// ---------------- Conv 3x3 VALID via bf16 MFMA implicit GEMM ----------------
// Round-4 verified structure (332 us, MfmaUtil 34%) + ONE change: odd-ID blocks
// s_sleep ~2.5k cyc at entry. Theory: the 2 co-resident blocks/CU run identical
// code launched simultaneously -> their 144 vmcnt(0)+barrier drains stay
// wall-clock ALIGNED, so neither block's compute covers the other's drain.
// The one-time stagger breaks lockstep permanently (same cadence, offset phase).
// Sigma is bitwise identical to r4/r9 (no data/order change) -> pure A/B on time.
__global__ __launch_bounds__(256, 2) void conv_mfma_kernel(const u16* __restrict__ xh,
                                                           const u16* __restrict__ whT,
                                                           float* __restrict__ sigma) {
    // xs chunk c = spq*264 + row*66 + col (spq = sp*4+q, row 0..3, col 0..65)
    __shared__ __align__(16) u16 xs[8*4*66*8];       // 33792 B
    // wsh: 2 buffers, each chunk c = q*288 + co (one split per buffer)
    __shared__ __align__(16) u16 wsh[2*4*288*8];     // 36864 B (total 70656 -> 2 blk/CU)

    const int tid  = threadIdx.x;
    const int wave = tid >> 6;
    const int lane = tid & 63;
    const int m16  = lane & 15;
    const int q    = lane >> 4;
    const int wr   = wave & 1;      // output row within block
    const int wc   = wave >> 1;     // co half (144 each)
    const int ow0  = blockIdx.x * 64;
    const int oh0  = blockIdx.y * 2;
    const int n    = blockIdx.z;

    // de-lockstep co-resident blocks (~2560 cyc one-time offset)
    const int bid = blockIdx.x + 2*(blockIdx.y + 63*blockIdx.z);
    if (bid & 1) __builtin_amdgcn_s_sleep(40);

    // ---- w staging: 1152 chunks [q][co]; wave distribution 5/5/4/4 issues ----
    const int w_nw   = (wave < 2) ? 5 : 4;
    const int w_base = (wave < 2) ? wave*320 : 640 + (wave-2)*256;
    int wsrc[5];
    #pragma unroll
    for (int i = 0; i < 5; ++i) {
        int c = w_base + i*64 + lane;            // < 1152 by construction
        const int cq  = c / 288;
        const int cco = c - cq*288;
        wsrc[i] = cco*256 + cq*8;                // + split*WTOT + s*WSTRIDE + ci0
    }

    // ---- x staging: 2112 chunks; issue idx = 4t+wave, t<9, idx<33 ----
    int xoff[9];
    #pragma unroll
    for (int t = 0; t < 9; ++t) {
        int c = (4*t + wave)*64 + lane;
        if (c > 2111) c = 2111;                  // unused (guarded at issue)
        const int spq = c / 264;
        const int rem = c - spq*264;
        const int row = rem / 66;
        const int col = rem - row*66;
        int gc = ow0 + col; if (gc > W-1) gc = W-1;   // clamp feeds discarded outputs
        xoff[t] = (spq >> 2)*XTOT + ((n*H + oh0 + row)*W + gc)*C + (spq & 3)*8;
    }

    // ---- fragment read offsets (u16 units) ----
    const int aoff = (q*264 + wr*66 + m16)*8;    // + (ky*66+kx)*8 + mt*128 ; lo +8448
    const int boff = (q*288 + wc*144 + m16)*8;   // + buf*9216 + j*128

    float4v acc[4][9];
    #pragma unroll
    for (int mt = 0; mt < 4; ++mt)
        #pragma unroll
        for (int j = 0; j < 9; ++j) acc[mt][j] = (float4v)(0.f);

    // ---- prologue: stage xs(ci0=0) and w unit0 (s=0, hi) into buf 0 ----
    #pragma unroll
    for (int t = 0; t < 9; ++t)
        if (t < 8 || wave == 0)
            __builtin_amdgcn_global_load_lds((const uint*)(xh + xoff[t]),
                                             (uint*)(xs + (4*t + wave)*512), 16, 0, 0);
    #pragma unroll
    for (int i = 0; i < 5; ++i)
        if (i < w_nw)
            __builtin_amdgcn_global_load_lds((const uint*)(whT + wsrc[i]),
                                             (uint*)(wsh + (w_base + i*64)*8), 16, 0, 0);
    __syncthreads();

    int buf = 0;
    for (int ci0 = 0; ci0 < C; ci0 += 32) {
        #pragma unroll
        for (int ky = 0; ky < 3; ++ky)
        #pragma unroll
        for (int kx = 0; kx < 3; ++kx) {
            const int s = ky*3 + kx;

            // ======== unit A (bh): issue bl(s) into buf^1, compute 72 MFMA ========
            {
                const int soff = WTOT + s*WSTRIDE + ci0;     // lo split, same s
                #pragma unroll
                for (int i = 0; i < 5; ++i)
                    if (i < w_nw)
                        __builtin_amdgcn_global_load_lds(
                            (const uint*)(whT + soff + wsrc[i]),
                            (uint*)(wsh + ((buf^1)*1152 + w_base + i*64)*8), 16, 0, 0);
            }
            const int ab = aoff + (ky*66 + kx)*8;
            short8 ah0 = *(const short8*)&xs[ab];
            short8 ah1 = *(const short8*)&xs[ab + 128];
            short8 ah2 = *(const short8*)&xs[ab + 256];
            short8 ah3 = *(const short8*)&xs[ab + 384];
            {
                short8 al0 = *(const short8*)&xs[ab + 8448];
                short8 al1 = *(const short8*)&xs[ab + 8448 + 128];
                short8 al2 = *(const short8*)&xs[ab + 8448 + 256];
                short8 al3 = *(const short8*)&xs[ab + 8448 + 384];
                const u16* wb = wsh + buf*9216 + boff;
                __builtin_amdgcn_s_setprio(1);
                #pragma unroll
                for (int j = 0; j < 9; ++j) {
                    short8 bh = *(const short8*)&wb[j*128];
                    acc[0][j] = __builtin_amdgcn_mfma_f32_16x16x32_bf16(ah0, bh, acc[0][j], 0, 0, 0);
                    acc[1][j] = __builtin_amdgcn_mfma_f32_16x16x32_bf16(ah1, bh, acc[1][j], 0, 0, 0);
                    acc[2][j] = __builtin_amdgcn_mfma_f32_16x16x32_bf16(ah2, bh, acc[2][j], 0, 0, 0);
                    acc[3][j] = __builtin_amdgcn_mfma_f32_16x16x32_bf16(ah3, bh, acc[3][j], 0, 0, 0);
                    acc[0][j] = __builtin_amdgcn_mfma_f32_16x16x32_bf16(al0, bh, acc[0][j], 0, 0, 0);
                    acc[1][j] = __builtin_amdgcn_mfma_f32_16x16x32_bf16(al1, bh, acc[1][j], 0, 0, 0);
                    acc[2][j] = __builtin_amdgcn_mfma_f32_16x16x32_bf16(al2, bh, acc[2][j], 0, 0, 0);
                    acc[3][j] = __builtin_amdgcn_mfma_f32_16x16x32_bf16(al3, bh, acc[3][j], 0, 0, 0);
                }
                __builtin_amdgcn_s_setprio(0);
            }
            __syncthreads();     // drains bl(s) loads; bh buffer readers done
            buf ^= 1;

            // ======== unit B (bl): issue next hi into buf^1 (+xs restage at s=8) ====
            if (!(ci0 == C-32 && s == 8)) {
                int ns = s + 1, nci = ci0;
                if (ns == 9) { ns = 0; nci += 32; }
                const int soff = ns*WSTRIDE + nci;           // hi split of next unit
                #pragma unroll
                for (int i = 0; i < 5; ++i)
                    if (i < w_nw)
                        __builtin_amdgcn_global_load_lds(
                            (const uint*)(whT + soff + wsrc[i]),
                            (uint*)(wsh + ((buf^1)*1152 + w_base + i*64)*8), 16, 0, 0);
                if (s == 8) {    // xs readers finished at unit A's barrier
                    #pragma unroll
                    for (int t = 0; t < 9; ++t)
                        if (t < 8 || wave == 0)
                            __builtin_amdgcn_global_load_lds(
                                (const uint*)(xh + xoff[t] + nci),
                                (uint*)(xs + (4*t + wave)*512), 16, 0, 0);
                }
            }
            {
                const u16* wb = wsh + buf*9216 + boff;
                __builtin_amdgcn_s_setprio(1);
                #pragma unroll
                for (int j = 0; j < 9; ++j) {
                    short8 bl = *(const short8*)&wb[j*128];
                    acc[0][j] = __builtin_amdgcn_mfma_f32_16x16x32_bf16(ah0, bl, acc[0][j], 0, 0, 0);
                    acc[1][j] = __builtin_amdgcn_mfma_f32_16x16x32_bf16(ah1, bl, acc[1][j], 0, 0, 0);
                    acc[2][j] = __builtin_amdgcn_mfma_f32_16x16x32_bf16(ah2, bl, acc[2][j], 0, 0, 0);
                    acc[3][j] = __builtin_amdgcn_mfma_f32_16x16x32_bf16(ah3, bl, acc[3][j], 0, 0, 0);
                }
                __builtin_amdgcn_s_setprio(0);
            }
            __syncthreads();     // drains next-unit hi (+xs) loads; bl readers done
            buf ^= 1;
        }
    }

    // store: D[row=q*4+r][col=m16]; pos = mt*16+q*4+r, co = wc*144+j*16+m16
    #pragma unroll
    for (int mt = 0; mt < 4; ++mt) {
        const int posb = mt*16 + q*4;
        #pragma unroll
        for (int j = 0; j < 9; ++j) {
            const int co = wc*144 + j*16 + m16;
            float* dst = sigma + (size_t)n*SNSTRIDE + (size_t)co*HW + (oh0 + wr)*OW;
            #pragma unroll
            for (int r = 0; r < 4; ++r) {
                const int ow = ow0 + posb + r;
                if (ow < OW) dst[ow] = acc[mt][j][r];
            }
        }
    }
}

// ---------------- Per-channel mean/var over (N, OH, OW) ----------------
__global__ __launch_bounds__(1024) void stats_kernel(const float* __restrict__ sigma,
                                                     const float* __restrict__ gamma,
                                                     const float* __restrict__ beta,
                                                     float* __restrict__ coef) {
    const int c = blockIdx.x;
    float sum = 0.f, sq = 0.f;
    for (int n = 0; n < N; ++n) {
        const float* sp = sigma + (size_t)n*SNSTRIDE + (size_t)c*HW;
        for (int i = threadIdx.x; i < HW; i += 1024) {
            float v = sp[i];
            sum += v; sq += v * v;
        }
    }
    for (int off = 32; off > 0; off >>= 1) {
        sum += __shfl_down(sum, off, 64);
        sq  += __shfl_down(sq,  off, 64);
    }
    __shared__ float ls[16], lq[16];
    const int wid = threadIdx.x >> 6, lane = threadIdx.x & 63;
    if (lane == 0) { ls[wid] = sum; lq[wid] = sq; }
    __syncthreads();
    if (threadIdx.x == 0) {
        float S = 0.f, Q = 0.f;
        #pragma unroll
        for (int i = 0; i < 16; ++i) { S += ls[i]; Q += lq[i]; }
        const float cnt = (float)(N * HW);
        float mean = S / cnt;
        float var  = Q / cnt - mean * mean;
        float a = gamma[c] * rsqrtf(var + EPS);
        coef[c]      = a;
        coef[CO + c] = beta[c] - mean * a;
    }
}

// ---------------- Fused normalize + softmax(288) + grouped dynamic 3x3 ----------------
// Round-10 change: r9's fuse ran 249 blocks = ~1 wave/SIMD -> fully latency-
// exposed (the 315 us tail's main cost). Split the 32 groups across 4 threads
// per position (tid = pos*4 + gc, 8 groups each) -> 4x waves (~15.5/CU) for
// latency hiding. Per-(g,c) numerator FP order unchanged; softmax denominator
// combined across the aligned 4-lane cluster via shfl_xor (rounding ~1e-7).
__global__ __launch_bounds__(256) void fuse_kernel(const float* __restrict__ x,
                                                   const float* __restrict__ sigma,
                                                   const float* __restrict__ coef,
                                                   float* __restrict__ outlo,
                                                   float* __restrict__ sums) {
    __shared__ float a[CO], b[CO];
    for (int i = threadIdx.x; i < CO; i += 256) {
        a[i] = coef[i];
        b[i] = coef[CO + i];
    }
    __syncthreads();

    const int t4 = blockIdx.x * 256 + threadIdx.x;
    if (t4 >= N * HW * 4) return;          // whole 4-lane clusters exit together
    const int gpos = t4 >> 2;
    const int gc   = t4 & 3;               // which 8-group slice this lane owns
    const int n  = gpos / HW;
    const int hw = gpos - n * HW;
    const int oh = hw / OW;
    const int ow = hw - oh * OW;

    const float* sp = sigma + (size_t)n * SNSTRIDE + hw;
    const float* xb = x + (size_t)n * XNSTRIDE + oh * W + ow;
    float* ob = outlo + (size_t)n * LONSTRIDE + hw;

    float sum = 0.f;
    for (int gl = 0; gl < 8; ++gl) {
        const int g = gc * 8 + gl;
        float acc[CPG];
        #pragma unroll
        for (int c = 0; c < CPG; ++c) acc[c] = 0.f;
        #pragma unroll
        for (int p = 0; p < 9; ++p) {
            const int ch = g * 9 + p;
            float s = sp[(size_t)ch * HW] * a[ch] + b[ch];
            float e = __expf(s);
            sum += e;
            const float* xr = xb + (size_t)(g * CPG) * XSLICE + (p / 3) * W + (p % 3);
            #pragma unroll
            for (int c = 0; c < CPG; ++c)
                acc[c] += xr[(size_t)c * XSLICE] * e;
        }
        #pragma unroll
        for (int c = 0; c < CPG; ++c)
            ob[(size_t)(g * CPG + c) * HW] = acc[c];
    }
    // combine softmax denominator across the 4 lanes of this position
    sum += __shfl_xor(sum, 1, 64);
    sum += __shfl_xor(sum, 2, 64);
    if (gc == 0) sums[gpos] = sum;
}

// ---------------- Bilinear align-corners upsample 126 -> 128 (+ softmax divide) ----
__global__ __launch_bounds__(256) void upsample_kernel(const float* __restrict__ lo,
                                                       const float* __restrict__ sums,
                                                       float* __restrict__ out) {
    const int idx = blockIdx.x * 256 + threadIdx.x;
    const int xi = idx & (W - 1);
    const int yi = (idx >> 7) & (H - 1);
    const int nc = idx >> 14;
    const int n  = nc >> 8;              // C = 256

    const float scale = 125.0f / 127.0f;
    const float sy = yi * scale;
    const float sx = xi * scale;
    int y0 = (int)sy;
    int x0 = (int)sx;
    float wy = sy - (float)y0;
    float wx = sx - (float)x0;
    int y1 = min(y0 + 1, OH - 1);
    int x1 = min(x0 + 1, OW - 1);

    const float* p  = lo + (size_t)nc * HW;
    const float* ps = sums + (size_t)n * HW;
    float v00 = p[y0 * OW + x0] / ps[y0 * OW + x0];
    float v01 = p[y0 * OW + x1] / ps[y0 * OW + x1];
    float v10 = p[y1 * OW + x0] / ps[y1 * OW + x0];
    float v11 = p[y1 * OW + x1] / ps[y1 * OW + x1];
    float top = v00 * (1.f - wx) + v01 * wx;
    float bot = v10 * (1.f - wx) + v11 * wx;
    out[idx] = top * (1.f - wy) + bot * wy;
}

extern "C" void kernel_launch(void* const* d_in, const int* in_sizes, int n_in,
                              void* d_out, int out_size, void* d_ws, size_t ws_size,
                              hipStream_t stream) {
    const float* x      = (const float*)d_in[0];
    const float* conv_w = (const float*)d_in[1];
    const float* gamma  = (const float*)d_in[2];
    const float* beta   = (const float*)d_in[3];
    float* out = (float*)d_out;
    float* ws  = (float*)d_ws;

    // workspace (floats):
    //   sigma : [0, 18289152)
    //   coef  : [18289152, +1024)
    //   outlo : [18290176, +16257024)   -- ALIASED with xh/xl (prep+conv finish first)
    //   sums  : aliased over whT (dead after conv, written by fuse, read by upsample)
    float* sigma = ws;
    float* coef  = ws + 18289152;
    float* outlo = ws + 18290176;
    u16* xhp = (u16*)(ws + 18290176);               // 16777216 u16 = 33.5 MB
    u16* xlp = xhp + (size_t)XTOT;                  // adjacent: xl = xh + XTOT
    u16* whT = xlp + (size_t)XTOT;                  // 663552 u16
    u16* wlT = whT + (size_t)WTOT;                  // adjacent: wl = wh + WTOT
    float* sums = (float*)whT;                      // 63504 floats, fits in w region
    // total ws usage ~143 MB

    split_x_kernel<<<dim3(16, 128, 4), 256, 0, stream>>>(x, xhp, xlp);
    split_w_kernel<<<(9*CO*256)/256, 256, 0, stream>>>(conv_w, whT, wlT);

    conv_mfma_kernel<<<dim3(2, 63, N), 256, 0, stream>>>(xhp, whT, sigma);

    stats_kernel<<<CO, 1024, 0, stream>>>(sigma, gamma, beta, coef);

    fuse_kernel<<<(N * HW * 4 + 255) / 256, 256, 0, stream>>>(x, sigma, coef, outlo, sums);

    upsample_kernel<<<(N * C * H * W) / 256, 256, 0, stream>>>(outlo, sums, out);
}

// Round 11
// 596.316 us; speedup vs baseline: 1.6475x; 1.0311x over previous
//
#include <hip/hip_runtime.h>
#include <hip/hip_bf16.h>
#include <math.h>

#define N 4
#define C 256
#define H 128
#define W 128
#define CO 288        // GROUP * K * K = 32 * 9
#define OH 126
#define OW 126
#define GROUP 32
#define CPG 8
#define EPS 1e-5f

#define HW (OH*OW)          // 15876
#define XSLICE (H*W)        // 16384
#define XNSTRIDE (C*H*W)    // 4194304
#define SNSTRIDE (CO*HW)    // 4572288
#define LONSTRIDE (C*HW)    // 4064256
#define WSTRIDE (CO*256)    // 73728 u16 per shift s
#define WTOT (9*CO*256)     // 663552 u16 per table (wlT = whT + WTOT)
#define XTOT (N*H*W*C)      // 16777216 u16 per table (xl = xh + XTOT)

typedef unsigned short u16;
typedef __attribute__((ext_vector_type(8))) short short8;
typedef __attribute__((ext_vector_type(4))) float float4v;

__device__ inline u16 f2bf(float v) {
    __hip_bfloat16 b = __float2bfloat16(v);
    return __builtin_bit_cast(u16, b);
}
__device__ inline float bf2f(u16 u) {
    __hip_bfloat16 b = __builtin_bit_cast(__hip_bfloat16, u);
    return __bfloat162float(b);
}

// ---------------- Prep: split x into bf16 hi/lo, transpose to NHWC ----------------
// xh/xl layout: [n][h][w][ci] (ci contiguous); xl MUST be at xh + XTOT.
__global__ __launch_bounds__(256) void split_x_kernel(const float* __restrict__ x,
                                                      u16* __restrict__ xh,
                                                      u16* __restrict__ xl) {
    const int ci = threadIdx.x;          // 0..255
    const int w0 = blockIdx.x * 8;       // 16 groups
    const int h  = blockIdx.y;
    const int n  = blockIdx.z;
    const float* src = x + ((size_t)(n*C + ci)*H + h)*W + w0;
    float4 v0 = *(const float4*)src;
    float4 v1 = *(const float4*)(src + 4);
    float vals[8] = {v0.x, v0.y, v0.z, v0.w, v1.x, v1.y, v1.z, v1.w};
    size_t obase = ((size_t)(n*H + h)*W + w0)*C + ci;
    #pragma unroll
    for (int dw = 0; dw < 8; ++dw) {
        float v = vals[dw];
        u16 hb = f2bf(v);
        xh[obase + (size_t)dw*C] = hb;
        xl[obase + (size_t)dw*C] = f2bf(v - bf2f(hb));
    }
}

// ---------------- Prep: split w into bf16 hi/lo, layout [s][co][ci] ----------------
__global__ __launch_bounds__(256) void split_w_kernel(const float* __restrict__ wgt,
                                                      u16* __restrict__ whT,
                                                      u16* __restrict__ wlT) {
    const int i = blockIdx.x*256 + threadIdx.x;  // < 9*288*256 = 663552
    const int ci = i & 255;
    const int co = (i >> 8) % CO;
    const int s  = i / (CO*256);
    float v = wgt[(size_t)co*(C*9) + (size_t)ci*9 + s];
    u16 hb = f2bf(v);
    whT[i] = hb;
    wlT[i] = f2bf(v - bf2f(hb));
}

// ---------------- Conv 3x3 VALID via bf16 MFMA implicit GEMM ----------------
// Round-11: one-barrier-per-shift restructure (r10's stagger A/B refuted the
// lockstep theory; per-shift budget shows ~3.4k cyc of stage/drain overhead per
// BARRIER WINDOW, so halve the windows and double the work inside each).
//
// Grid (2, 32, N) = 256 blocks = exactly 1 block/CU; block 512 = 8 waves
// (2/SIMD, same as before). Block: 4 output rows x 64 pos x 288 co.
// Wave (wr 0..3, wc 0..1) = 1 row x 64 pos x 144 co; acc[4 mt][9 j] float4 and
// the exact r4/r9 fragment/FP order (ah*bh, al*bh, ah*bl per shift; s, ci0
// ascending) -> sigma bitwise identical.
//
// LDS (124928 B): xs 51200 B (both splits, 6 rows x 66 cols, +pad) single-buf;
// wsh 2 x 36864 B holding BOTH splits of one shift. Per shift: stage shift s+1
// (both splits) into buf^1, compute all 108 MFMA/wave from buf, ONE
// vmcnt(0)-barrier -- loads aged a full 4.2k-cyc MFMA phase, drain ~free.
// 81 barriers total vs r4's 145. xs restage: one cheap extra barrier at s==8
// (readers-done fence; nothing outstanding), loads drain at shift-8's barrier.
__global__ __launch_bounds__(512, 2) void conv_mfma_kernel(const u16* __restrict__ xh,
                                                           const u16* __restrict__ whT,
                                                           float* __restrict__ sigma) {
    // xs chunk c = spq*396 + row*66 + col (spq = sp*4+q, row 0..5, col 0..65)
    // u16 idx = c*8 ; 3168 chunks + 32 pad (clamped staging tail)
    __shared__ __align__(16) u16 xs[25600];          // 51200 B
    // wsh buf: chunk c = sp*1152 + q*288 + co ; u16 idx = buf*18432 + c*8
    __shared__ __align__(16) u16 wsh[2*18432];       // 73728 B  (total 124928 B)

    const int tid  = threadIdx.x;
    const int wave = tid >> 6;
    const int lane = tid & 63;
    const int m16  = lane & 15;
    const int q    = lane >> 4;
    const int wr   = wave & 3;      // output row within block (0..3)
    const int wc   = wave >> 2;     // co half (144 each)
    const int ow0  = blockIdx.x * 64;
    const int oh0  = blockIdx.y * 4;
    const int n    = blockIdx.z;

    // ---- w staging: 2304 chunks (both splits); wave issues 5/5/5/5/4/4/4/4 ----
    const int w_n    = (wave < 4) ? 5 : 4;
    const int w_base = (wave < 4) ? wave*320 : 1280 + (wave-4)*256;
    int wsrc[5];
    #pragma unroll
    for (int i = 0; i < 5; ++i) {
        int c = w_base + i*64 + lane;            // < 2304 by construction
        const int sp  = c / 1152;
        const int rem = c - sp*1152;
        const int qc  = rem / 288;
        const int co  = rem - qc*288;
        wsrc[i] = sp*WTOT + co*256 + qc*8;       // + s*WSTRIDE + ci0
    }

    // ---- x staging: 3168 chunks; issue idx = 8t+wave, t<7 (t==6 only wave<2) ----
    int xoff[7];
    #pragma unroll
    for (int t = 0; t < 7; ++t) {
        int c = (8*t + wave)*64 + lane;
        if (c > 3167) c = 3167;                  // pad tail: source clamped, dest in pad
        const int spq = c / 396;
        const int rem = c - spq*396;
        const int row = rem / 66;
        const int col = rem - row*66;
        int gr = oh0 + row; if (gr > H-1) gr = H-1;   // clamp feeds discarded outputs
        int gc = ow0 + col; if (gc > W-1) gc = W-1;
        xoff[t] = (spq >> 2)*XTOT + ((n*H + gr)*W + gc)*C + (spq & 3)*8;
    }

    // ---- fragment read offsets (u16 units) ----
    const int aoff = (q*396 + wr*66 + m16)*8;    // + (ky*66+kx)*8 + mt*128 ; lo +12672
    const int boff = (q*288 + wc*144 + m16)*8;   // + buf*18432 + j*128 ; lo +9216

    float4v acc[4][9];
    #pragma unroll
    for (int mt = 0; mt < 4; ++mt)
        #pragma unroll
        for (int j = 0; j < 9; ++j) acc[mt][j] = (float4v)(0.f);

    // ---- prologue: stage xs(ci0=0) and w(s=0, ci0=0, both splits) into buf 0 ----
    #pragma unroll
    for (int t = 0; t < 7; ++t)
        if (t < 6 || wave < 2)
            __builtin_amdgcn_global_load_lds((const uint*)(xh + xoff[t]),
                                             (uint*)(xs + (8*t + wave)*512), 16, 0, 0);
    #pragma unroll
    for (int i = 0; i < 5; ++i)
        if (i < w_n)
            __builtin_amdgcn_global_load_lds((const uint*)(whT + wsrc[i]),
                                             (uint*)(wsh + (w_base + i*64)*8), 16, 0, 0);
    __syncthreads();

    int buf = 0;
    for (int ci0 = 0; ci0 < C; ci0 += 32) {
        #pragma unroll 1
        for (int s = 0; s < 9; ++s) {
            // stage next shift (same ci0) into buf^1 -- ages through this compute
            if (s < 8) {
                const int soff = (s+1)*WSTRIDE + ci0;
                #pragma unroll
                for (int i = 0; i < 5; ++i)
                    if (i < w_n)
                        __builtin_amdgcn_global_load_lds(
                            (const uint*)(whT + soff + wsrc[i]),
                            (uint*)(wsh + ((buf^1)*18432 + (w_base + i*64)*8)), 16, 0, 0);
            }

            const int ky = s / 3;
            const int kx = s - 3*ky;
            const int ab = aoff + (ky*66 + kx)*8;
            short8 ah0 = *(const short8*)&xs[ab];
            short8 ah1 = *(const short8*)&xs[ab + 128];
            short8 ah2 = *(const short8*)&xs[ab + 256];
            short8 ah3 = *(const short8*)&xs[ab + 384];
            short8 al0 = *(const short8*)&xs[ab + 12672];
            short8 al1 = *(const short8*)&xs[ab + 12672 + 128];
            short8 al2 = *(const short8*)&xs[ab + 12672 + 256];
            short8 al3 = *(const short8*)&xs[ab + 12672 + 384];

            if (s == 8) {
                // all waves' xs reads (above) complete at this fence; nothing
                // else outstanding -> cheap barrier. Then restage xs + w(0,nci)
                // into buf^1; both drain at this shift's ending barrier after
                // aging the full MFMA phase.
                __syncthreads();
                const int nci = ci0 + 32;
                if (nci < C) {
                    #pragma unroll
                    for (int t = 0; t < 7; ++t)
                        if (t < 6 || wave < 2)
                            __builtin_amdgcn_global_load_lds(
                                (const uint*)(xh + xoff[t] + nci),
                                (uint*)(xs + (8*t + wave)*512), 16, 0, 0);
                    #pragma unroll
                    for (int i = 0; i < 5; ++i)
                        if (i < w_n)
                            __builtin_amdgcn_global_load_lds(
                                (const uint*)(whT + nci + wsrc[i]),
                                (uint*)(wsh + ((buf^1)*18432 + (w_base + i*64)*8)), 16, 0, 0);
                }
            }

            const u16* wb = wsh + buf*18432 + boff;
            __builtin_amdgcn_s_setprio(1);
            #pragma unroll
            for (int j = 0; j < 9; ++j) {        // pass 1: bh (ah then al)
                short8 bh = *(const short8*)&wb[j*128];
                acc[0][j] = __builtin_amdgcn_mfma_f32_16x16x32_bf16(ah0, bh, acc[0][j], 0, 0, 0);
                acc[1][j] = __builtin_amdgcn_mfma_f32_16x16x32_bf16(ah1, bh, acc[1][j], 0, 0, 0);
                acc[2][j] = __builtin_amdgcn_mfma_f32_16x16x32_bf16(ah2, bh, acc[2][j], 0, 0, 0);
                acc[3][j] = __builtin_amdgcn_mfma_f32_16x16x32_bf16(ah3, bh, acc[3][j], 0, 0, 0);
                acc[0][j] = __builtin_amdgcn_mfma_f32_16x16x32_bf16(al0, bh, acc[0][j], 0, 0, 0);
                acc[1][j] = __builtin_amdgcn_mfma_f32_16x16x32_bf16(al1, bh, acc[1][j], 0, 0, 0);
                acc[2][j] = __builtin_amdgcn_mfma_f32_16x16x32_bf16(al2, bh, acc[2][j], 0, 0, 0);
                acc[3][j] = __builtin_amdgcn_mfma_f32_16x16x32_bf16(al3, bh, acc[3][j], 0, 0, 0);
            }
            #pragma unroll
            for (int j = 0; j < 9; ++j) {        // pass 2: bl (ah only)
                short8 bl = *(const short8*)&wb[9216 + j*128];
                acc[0][j] = __builtin_amdgcn_mfma_f32_16x16x32_bf16(ah0, bl, acc[0][j], 0, 0, 0);
                acc[1][j] = __builtin_amdgcn_mfma_f32_16x16x32_bf16(ah1, bl, acc[1][j], 0, 0, 0);
                acc[2][j] = __builtin_amdgcn_mfma_f32_16x16x32_bf16(ah2, bl, acc[2][j], 0, 0, 0);
                acc[3][j] = __builtin_amdgcn_mfma_f32_16x16x32_bf16(ah3, bl, acc[3][j], 0, 0, 0);
            }
            __builtin_amdgcn_s_setprio(0);

            __syncthreads();   // buf readers done; buf^1 loads drained (aged full shift)
            buf ^= 1;
        }
    }

    // store: D[row=q*4+r][col=m16]; pos = mt*16+q*4+r, co = wc*144+j*16+m16
    const int oh = oh0 + wr;
    if (oh < OH) {
        #pragma unroll
        for (int mt = 0; mt < 4; ++mt) {
            const int posb = mt*16 + q*4;
            #pragma unroll
            for (int j = 0; j < 9; ++j) {
                const int co = wc*144 + j*16 + m16;
                float* dst = sigma + (size_t)n*SNSTRIDE + (size_t)co*HW + oh*OW;
                #pragma unroll
                for (int r = 0; r < 4; ++r) {
                    const int ow = ow0 + posb + r;
                    if (ow < OW) dst[ow] = acc[mt][j][r];
                }
            }
        }
    }
}

// ---------------- Per-channel mean/var over (N, OH, OW) ----------------
__global__ __launch_bounds__(1024) void stats_kernel(const float* __restrict__ sigma,
                                                     const float* __restrict__ gamma,
                                                     const float* __restrict__ beta,
                                                     float* __restrict__ coef) {
    const int c = blockIdx.x;
    float sum = 0.f, sq = 0.f;
    for (int n = 0; n < N; ++n) {
        const float* sp = sigma + (size_t)n*SNSTRIDE + (size_t)c*HW;
        for (int i = threadIdx.x; i < HW; i += 1024) {
            float v = sp[i];
            sum += v; sq += v * v;
        }
    }
    for (int off = 32; off > 0; off >>= 1) {
        sum += __shfl_down(sum, off, 64);
        sq  += __shfl_down(sq,  off, 64);
    }
    __shared__ float ls[16], lq[16];
    const int wid = threadIdx.x >> 6, lane = threadIdx.x & 63;
    if (lane == 0) { ls[wid] = sum; lq[wid] = sq; }
    __syncthreads();
    if (threadIdx.x == 0) {
        float S = 0.f, Q = 0.f;
        #pragma unroll
        for (int i = 0; i < 16; ++i) { S += ls[i]; Q += lq[i]; }
        const float cnt = (float)(N * HW);
        float mean = S / cnt;
        float var  = Q / cnt - mean * mean;
        float a = gamma[c] * rsqrtf(var + EPS);
        coef[c]      = a;
        coef[CO + c] = beta[c] - mean * a;
    }
}

// ---------------- Fused normalize + softmax(288) + grouped dynamic 3x3 ----------------
// 4 threads per position (tid = pos*4 + gc, 8 groups each) for latency hiding;
// single pass, divide deferred to upsample (sums[]).
__global__ __launch_bounds__(256) void fuse_kernel(const float* __restrict__ x,
                                                   const float* __restrict__ sigma,
                                                   const float* __restrict__ coef,
                                                   float* __restrict__ outlo,
                                                   float* __restrict__ sums) {
    __shared__ float a[CO], b[CO];
    for (int i = threadIdx.x; i < CO; i += 256) {
        a[i] = coef[i];
        b[i] = coef[CO + i];
    }
    __syncthreads();

    const int t4 = blockIdx.x * 256 + threadIdx.x;
    if (t4 >= N * HW * 4) return;          // whole 4-lane clusters exit together
    const int gpos = t4 >> 2;
    const int gc   = t4 & 3;               // which 8-group slice this lane owns
    const int n  = gpos / HW;
    const int hw = gpos - n * HW;
    const int oh = hw / OW;
    const int ow = hw - oh * OW;

    const float* sp = sigma + (size_t)n * SNSTRIDE + hw;
    const float* xb = x + (size_t)n * XNSTRIDE + oh * W + ow;
    float* ob = outlo + (size_t)n * LONSTRIDE + hw;

    float sum = 0.f;
    for (int gl = 0; gl < 8; ++gl) {
        const int g = gc * 8 + gl;
        float acc[CPG];
        #pragma unroll
        for (int c = 0; c < CPG; ++c) acc[c] = 0.f;
        #pragma unroll
        for (int p = 0; p < 9; ++p) {
            const int ch = g * 9 + p;
            float s = sp[(size_t)ch * HW] * a[ch] + b[ch];
            float e = __expf(s);
            sum += e;
            const float* xr = xb + (size_t)(g * CPG) * XSLICE + (p / 3) * W + (p % 3);
            #pragma unroll
            for (int c = 0; c < CPG; ++c)
                acc[c] += xr[(size_t)c * XSLICE] * e;
        }
        #pragma unroll
        for (int c = 0; c < CPG; ++c)
            ob[(size_t)(g * CPG + c) * HW] = acc[c];
    }
    // combine softmax denominator across the 4 lanes of this position
    sum += __shfl_xor(sum, 1, 64);
    sum += __shfl_xor(sum, 2, 64);
    if (gc == 0) sums[gpos] = sum;
}

// ---------------- Bilinear align-corners upsample 126 -> 128 (+ softmax divide) ----
__global__ __launch_bounds__(256) void upsample_kernel(const float* __restrict__ lo,
                                                       const float* __restrict__ sums,
                                                       float* __restrict__ out) {
    const int idx = blockIdx.x * 256 + threadIdx.x;
    const int xi = idx & (W - 1);
    const int yi = (idx >> 7) & (H - 1);
    const int nc = idx >> 14;
    const int n  = nc >> 8;              // C = 256

    const float scale = 125.0f / 127.0f;
    const float sy = yi * scale;
    const float sx = xi * scale;
    int y0 = (int)sy;
    int x0 = (int)sx;
    float wy = sy - (float)y0;
    float wx = sx - (float)x0;
    int y1 = min(y0 + 1, OH - 1);
    int x1 = min(x0 + 1, OW - 1);

    const float* p  = lo + (size_t)nc * HW;
    const float* ps = sums + (size_t)n * HW;
    float v00 = p[y0 * OW + x0] / ps[y0 * OW + x0];
    float v01 = p[y0 * OW + x1] / ps[y0 * OW + x1];
    float v10 = p[y1 * OW + x0] / ps[y1 * OW + x0];
    float v11 = p[y1 * OW + x1] / ps[y1 * OW + x1];
    float top = v00 * (1.f - wx) + v01 * wx;
    float bot = v10 * (1.f - wx) + v11 * wx;
    out[idx] = top * (1.f - wy) + bot * wy;
}

extern "C" void kernel_launch(void* const* d_in, const int* in_sizes, int n_in,
                              void* d_out, int out_size, void* d_ws, size_t ws_size,
                              hipStream_t stream) {
    const float* x      = (const float*)d_in[0];
    const float* conv_w = (const float*)d_in[1];
    const float* gamma  = (const float*)d_in[2];
    const float* beta   = (const float*)d_in[3];
    float* out = (float*)d_out;
    float* ws  = (float*)d_ws;

    // workspace (floats):
    //   sigma : [0, 18289152)
    //   coef  : [18289152, +1024)
    //   outlo : [18290176, +16257024)   -- ALIASED with xh/xl (prep+conv finish first)
    //   sums  : aliased over whT (dead after conv, written by fuse, read by upsample)
    float* sigma = ws;
    float* coef  = ws + 18289152;
    float* outlo = ws + 18290176;
    u16* xhp = (u16*)(ws + 18290176);               // 16777216 u16 = 33.5 MB
    u16* xlp = xhp + (size_t)XTOT;                  // adjacent: xl = xh + XTOT
    u16* whT = xlp + (size_t)XTOT;                  // 663552 u16
    u16* wlT = whT + (size_t)WTOT;                  // adjacent: wl = wh + WTOT
    float* sums = (float*)whT;                      // 63504 floats, fits in w region
    // total ws usage ~143 MB

    split_x_kernel<<<dim3(16, 128, 4), 256, 0, stream>>>(x, xhp, xlp);
    split_w_kernel<<<(9*CO*256)/256, 256, 0, stream>>>(conv_w, whT, wlT);

    conv_mfma_kernel<<<dim3(2, 32, N), 512, 0, stream>>>(xhp, whT, sigma);

    stats_kernel<<<CO, 1024, 0, stream>>>(sigma, gamma, beta, coef);

    fuse_kernel<<<(N * HW * 4 + 255) / 256, 256, 0, stream>>>(x, sigma, coef, outlo, sums);

    upsample_kernel<<<(N * C * H * W) / 256, 256, 0, stream>>>(outlo, sums, out);
}

// Round 12
// 550.931 us; speedup vs baseline: 1.7832x; 1.0824x over previous
//
#include <hip/hip_runtime.h>
#include <hip/hip_bf16.h>
#include <math.h>

#define N 4
#define C 256
#define H 128
#define W 128
#define CO 288        // GROUP * K * K = 32 * 9
#define OH 126
#define OW 126
#define GROUP 32
#define CPG 8
#define EPS 1e-5f

#define HW (OH*OW)          // 15876
#define XSLICE (H*W)        // 16384
#define XNSTRIDE (C*H*W)    // 4194304
#define SNSTRIDE (CO*HW)    // 4572288
#define LONSTRIDE (C*HW)    // 4064256
#define WSTRIDE (CO*256)    // 73728 u16 per shift s
#define WTOT (9*CO*256)     // 663552 u16 per table (wlT = whT + WTOT)
#define XTOT (N*H*W*C)      // 16777216 u16 per table (xl = xh + XTOT)

typedef unsigned short u16;
typedef __attribute__((ext_vector_type(8))) short short8;
typedef __attribute__((ext_vector_type(4))) float float4v;

__device__ inline u16 f2bf(float v) {
    __hip_bfloat16 b = __float2bfloat16(v);
    return __builtin_bit_cast(u16, b);
}
__device__ inline float bf2f(u16 u) {
    __hip_bfloat16 b = __builtin_bit_cast(__hip_bfloat16, u);
    return __bfloat162float(b);
}

// ---------------- Prep: split x into bf16 hi/lo, transpose to NHWC ----------------
// xh/xl layout: [n][h][w][ci] (ci contiguous); xl MUST be at xh + XTOT.
__global__ __launch_bounds__(256) void split_x_kernel(const float* __restrict__ x,
                                                      u16* __restrict__ xh,
                                                      u16* __restrict__ xl) {
    const int ci = threadIdx.x;          // 0..255
    const int w0 = blockIdx.x * 8;       // 16 groups
    const int h  = blockIdx.y;
    const int n  = blockIdx.z;
    const float* src = x + ((size_t)(n*C + ci)*H + h)*W + w0;
    float4 v0 = *(const float4*)src;
    float4 v1 = *(const float4*)(src + 4);
    float vals[8] = {v0.x, v0.y, v0.z, v0.w, v1.x, v1.y, v1.z, v1.w};
    size_t obase = ((size_t)(n*H + h)*W + w0)*C + ci;
    #pragma unroll
    for (int dw = 0; dw < 8; ++dw) {
        float v = vals[dw];
        u16 hb = f2bf(v);
        xh[obase + (size_t)dw*C] = hb;
        xl[obase + (size_t)dw*C] = f2bf(v - bf2f(hb));
    }
}

// ---------------- Prep: split w into bf16 hi/lo, layout [s][co][ci] ----------------
__global__ __launch_bounds__(256) void split_w_kernel(const float* __restrict__ wgt,
                                                      u16* __restrict__ whT,
                                                      u16* __restrict__ wlT) {
    const int i = blockIdx.x*256 + threadIdx.x;  // < 9*288*256 = 663552
    const int ci = i & 255;
    const int co = (i >> 8) % CO;
    const int s  = i / (CO*256);
    float v = wgt[(size_t)co*(C*9) + (size_t)ci*9 + s];
    u16 hb = f2bf(v);
    whT[i] = hb;
    wlT[i] = f2bf(v - bf2f(hb));
}

// ---------------- Conv 3x3 VALID via bf16 MFMA implicit GEMM ----------------
// VERBATIM round-11 (313 us, MfmaUtil 36%): one-barrier-per-shift, 1 block/CU,
// 512 threads, 4 rows x 64 pos x 288 co, full-shift wsh double-buffer.
// Structural ceiling of this 2-phase-like schedule is ~36% MfmaUtil (m233);
// further conv gains need the 8-phase counted-vmcnt port (high risk, parked).
__global__ __launch_bounds__(512, 2) void conv_mfma_kernel(const u16* __restrict__ xh,
                                                           const u16* __restrict__ whT,
                                                           float* __restrict__ sigma) {
    // xs chunk c = spq*396 + row*66 + col (spq = sp*4+q, row 0..5, col 0..65)
    // u16 idx = c*8 ; 3168 chunks + 32 pad (clamped staging tail)
    __shared__ __align__(16) u16 xs[25600];          // 51200 B
    // wsh buf: chunk c = sp*1152 + q*288 + co ; u16 idx = buf*18432 + c*8
    __shared__ __align__(16) u16 wsh[2*18432];       // 73728 B  (total 124928 B)

    const int tid  = threadIdx.x;
    const int wave = tid >> 6;
    const int lane = tid & 63;
    const int m16  = lane & 15;
    const int q    = lane >> 4;
    const int wr   = wave & 3;      // output row within block (0..3)
    const int wc   = wave >> 2;     // co half (144 each)
    const int ow0  = blockIdx.x * 64;
    const int oh0  = blockIdx.y * 4;
    const int n    = blockIdx.z;

    // ---- w staging: 2304 chunks (both splits); wave issues 5/5/5/5/4/4/4/4 ----
    const int w_n    = (wave < 4) ? 5 : 4;
    const int w_base = (wave < 4) ? wave*320 : 1280 + (wave-4)*256;
    int wsrc[5];
    #pragma unroll
    for (int i = 0; i < 5; ++i) {
        int c = w_base + i*64 + lane;            // < 2304 by construction
        const int sp  = c / 1152;
        const int rem = c - sp*1152;
        const int qc  = rem / 288;
        const int co  = rem - qc*288;
        wsrc[i] = sp*WTOT + co*256 + qc*8;       // + s*WSTRIDE + ci0
    }

    // ---- x staging: 3168 chunks; issue idx = 8t+wave, t<7 (t==6 only wave<2) ----
    int xoff[7];
    #pragma unroll
    for (int t = 0; t < 7; ++t) {
        int c = (8*t + wave)*64 + lane;
        if (c > 3167) c = 3167;                  // pad tail: source clamped, dest in pad
        const int spq = c / 396;
        const int rem = c - spq*396;
        const int row = rem / 66;
        const int col = rem - row*66;
        int gr = oh0 + row; if (gr > H-1) gr = H-1;   // clamp feeds discarded outputs
        int gc = ow0 + col; if (gc > W-1) gc = W-1;
        xoff[t] = (spq >> 2)*XTOT + ((n*H + gr)*W + gc)*C + (spq & 3)*8;
    }

    // ---- fragment read offsets (u16 units) ----
    const int aoff = (q*396 + wr*66 + m16)*8;    // + (ky*66+kx)*8 + mt*128 ; lo +12672
    const int boff = (q*288 + wc*144 + m16)*8;   // + buf*18432 + j*128 ; lo +9216

    float4v acc[4][9];
    #pragma unroll
    for (int mt = 0; mt < 4; ++mt)
        #pragma unroll
        for (int j = 0; j < 9; ++j) acc[mt][j] = (float4v)(0.f);

    // ---- prologue: stage xs(ci0=0) and w(s=0, ci0=0, both splits) into buf 0 ----
    #pragma unroll
    for (int t = 0; t < 7; ++t)
        if (t < 6 || wave < 2)
            __builtin_amdgcn_global_load_lds((const uint*)(xh + xoff[t]),
                                             (uint*)(xs + (8*t + wave)*512), 16, 0, 0);
    #pragma unroll
    for (int i = 0; i < 5; ++i)
        if (i < w_n)
            __builtin_amdgcn_global_load_lds((const uint*)(whT + wsrc[i]),
                                             (uint*)(wsh + (w_base + i*64)*8), 16, 0, 0);
    __syncthreads();

    int buf = 0;
    for (int ci0 = 0; ci0 < C; ci0 += 32) {
        #pragma unroll 1
        for (int s = 0; s < 9; ++s) {
            // stage next shift (same ci0) into buf^1 -- ages through this compute
            if (s < 8) {
                const int soff = (s+1)*WSTRIDE + ci0;
                #pragma unroll
                for (int i = 0; i < 5; ++i)
                    if (i < w_n)
                        __builtin_amdgcn_global_load_lds(
                            (const uint*)(whT + soff + wsrc[i]),
                            (uint*)(wsh + ((buf^1)*18432 + (w_base + i*64)*8)), 16, 0, 0);
            }

            const int ky = s / 3;
            const int kx = s - 3*ky;
            const int ab = aoff + (ky*66 + kx)*8;
            short8 ah0 = *(const short8*)&xs[ab];
            short8 ah1 = *(const short8*)&xs[ab + 128];
            short8 ah2 = *(const short8*)&xs[ab + 256];
            short8 ah3 = *(const short8*)&xs[ab + 384];
            short8 al0 = *(const short8*)&xs[ab + 12672];
            short8 al1 = *(const short8*)&xs[ab + 12672 + 128];
            short8 al2 = *(const short8*)&xs[ab + 12672 + 256];
            short8 al3 = *(const short8*)&xs[ab + 12672 + 384];

            if (s == 8) {
                // all waves' xs reads (above) complete at this fence; nothing
                // else outstanding -> cheap barrier. Then restage xs + w(0,nci)
                // into buf^1; both drain at this shift's ending barrier after
                // aging the full MFMA phase.
                __syncthreads();
                const int nci = ci0 + 32;
                if (nci < C) {
                    #pragma unroll
                    for (int t = 0; t < 7; ++t)
                        if (t < 6 || wave < 2)
                            __builtin_amdgcn_global_load_lds(
                                (const uint*)(xh + xoff[t] + nci),
                                (uint*)(xs + (8*t + wave)*512), 16, 0, 0);
                    #pragma unroll
                    for (int i = 0; i < 5; ++i)
                        if (i < w_n)
                            __builtin_amdgcn_global_load_lds(
                                (const uint*)(whT + nci + wsrc[i]),
                                (uint*)(wsh + ((buf^1)*18432 + (w_base + i*64)*8)), 16, 0, 0);
                }
            }

            const u16* wb = wsh + buf*18432 + boff;
            __builtin_amdgcn_s_setprio(1);
            #pragma unroll
            for (int j = 0; j < 9; ++j) {        // pass 1: bh (ah then al)
                short8 bh = *(const short8*)&wb[j*128];
                acc[0][j] = __builtin_amdgcn_mfma_f32_16x16x32_bf16(ah0, bh, acc[0][j], 0, 0, 0);
                acc[1][j] = __builtin_amdgcn_mfma_f32_16x16x32_bf16(ah1, bh, acc[1][j], 0, 0, 0);
                acc[2][j] = __builtin_amdgcn_mfma_f32_16x16x32_bf16(ah2, bh, acc[2][j], 0, 0, 0);
                acc[3][j] = __builtin_amdgcn_mfma_f32_16x16x32_bf16(ah3, bh, acc[3][j], 0, 0, 0);
                acc[0][j] = __builtin_amdgcn_mfma_f32_16x16x32_bf16(al0, bh, acc[0][j], 0, 0, 0);
                acc[1][j] = __builtin_amdgcn_mfma_f32_16x16x32_bf16(al1, bh, acc[1][j], 0, 0, 0);
                acc[2][j] = __builtin_amdgcn_mfma_f32_16x16x32_bf16(al2, bh, acc[2][j], 0, 0, 0);
                acc[3][j] = __builtin_amdgcn_mfma_f32_16x16x32_bf16(al3, bh, acc[3][j], 0, 0, 0);
            }
            #pragma unroll
            for (int j = 0; j < 9; ++j) {        // pass 2: bl (ah only)
                short8 bl = *(const short8*)&wb[9216 + j*128];
                acc[0][j] = __builtin_amdgcn_mfma_f32_16x16x32_bf16(ah0, bl, acc[0][j], 0, 0, 0);
                acc[1][j] = __builtin_amdgcn_mfma_f32_16x16x32_bf16(ah1, bl, acc[1][j], 0, 0, 0);
                acc[2][j] = __builtin_amdgcn_mfma_f32_16x16x32_bf16(ah2, bl, acc[2][j], 0, 0, 0);
                acc[3][j] = __builtin_amdgcn_mfma_f32_16x16x32_bf16(ah3, bl, acc[3][j], 0, 0, 0);
            }
            __builtin_amdgcn_s_setprio(0);

            __syncthreads();   // buf readers done; buf^1 loads drained (aged full shift)
            buf ^= 1;
        }
    }

    // store: D[row=q*4+r][col=m16]; pos = mt*16+q*4+r, co = wc*144+j*16+m16
    const int oh = oh0 + wr;
    if (oh < OH) {
        #pragma unroll
        for (int mt = 0; mt < 4; ++mt) {
            const int posb = mt*16 + q*4;
            #pragma unroll
            for (int j = 0; j < 9; ++j) {
                const int co = wc*144 + j*16 + m16;
                float* dst = sigma + (size_t)n*SNSTRIDE + (size_t)co*HW + oh*OW;
                #pragma unroll
                for (int r = 0; r < 4; ++r) {
                    const int ow = ow0 + posb + r;
                    if (ow < OW) dst[ow] = acc[mt][j][r];
                }
            }
        }
    }
}

// ---------------- Per-channel mean/var over (N, OH, OW) ----------------
__global__ __launch_bounds__(1024) void stats_kernel(const float* __restrict__ sigma,
                                                     const float* __restrict__ gamma,
                                                     const float* __restrict__ beta,
                                                     float* __restrict__ coef) {
    const int c = blockIdx.x;
    float sum = 0.f, sq = 0.f;
    for (int n = 0; n < N; ++n) {
        const float* sp = sigma + (size_t)n*SNSTRIDE + (size_t)c*HW;
        for (int i = threadIdx.x; i < HW; i += 1024) {
            float v = sp[i];
            sum += v; sq += v * v;
        }
    }
    for (int off = 32; off > 0; off >>= 1) {
        sum += __shfl_down(sum, off, 64);
        sq  += __shfl_down(sq,  off, 64);
    }
    __shared__ float ls[16], lq[16];
    const int wid = threadIdx.x >> 6, lane = threadIdx.x & 63;
    if (lane == 0) { ls[wid] = sum; lq[wid] = sq; }
    __syncthreads();
    if (threadIdx.x == 0) {
        float S = 0.f, Q = 0.f;
        #pragma unroll
        for (int i = 0; i < 16; ++i) { S += ls[i]; Q += lq[i]; }
        const float cnt = (float)(N * HW);
        float mean = S / cnt;
        float var  = Q / cnt - mean * mean;
        float a = gamma[c] * rsqrtf(var + EPS);
        coef[c]      = a;
        coef[CO + c] = beta[c] - mean * a;
    }
}

// ---------------- Fused normalize + softmax(288) + grouped dynamic 3x3 ----------------
// Round-12 rewrite: LDS-staged x. One block per (n, oh) output row, 512 threads.
// Per group g (sequential), the block stages x[g*8..+8][oh..oh+2][0..127] (12 KB,
// double-buffered; g+1 staged during g's compute) with coalesced float4 loads;
// thread (pos 0..125, gc 0..3) computes channels gc*2, gc*2+1 from LDS.
// Replaces per-thread scattered 64KB-stride x loads (~585 MB effective L2/L3
// traffic, 9x amplification) with ~198 MB coalesced staging.
// Per-output FP order identical to r10/r11 (p ascending into same accumulator)
// -> outlo bitwise identical. sums order = sequential g,p (r9's order).
__global__ __launch_bounds__(512) void fuse_kernel(const float* __restrict__ x,
                                                   const float* __restrict__ sigma,
                                                   const float* __restrict__ coef,
                                                   float* __restrict__ outlo,
                                                   float* __restrict__ sums) {
    __shared__ float a[CO], b[CO];
    __shared__ float xbuf[2][8*3*128];           // 2 x 12288 B (+ a/b = 27 KB)

    const int tid = threadIdx.x;
    for (int i = tid; i < CO; i += 512) {
        a[i] = coef[i];
        b[i] = coef[CO + i];
    }

    const int oh = blockIdx.x % OH;
    const int n  = blockIdx.x / OH;
    const float* xrow = x + (size_t)n * XNSTRIDE + (size_t)oh * W;

    // stage group g's slab: rows (ch*3+r) of 128 f32; 768 float4 chunks total
    // chunk f: row = f>>5 (0..23), w4 = f&31; ch = row/3, r = row%3
    const int f0row = tid >> 5, f0w4 = tid & 31;                 // f = tid (<512)
    const int f1row = (512 + tid) >> 5, f1w4 = tid & 31;         // f = 512+tid (tid<256)

    const int pos = tid >> 2;        // 0..127 (active < 126)
    const int gc  = tid & 3;         // channel pair selector
    const bool act = pos < OW;
    const int hw = oh * OW + pos;
    const float* sp = sigma + (size_t)n * SNSTRIDE + hw;
    float* ob = outlo + (size_t)n * LONSTRIDE + hw;

    // prologue: stage g=0 into buf 0
    {
        const float* src = xrow;     // g = 0
        const int ch = f0row / 3, r = f0row - 3*ch;
        *(float4*)&xbuf[0][f0row*128 + f0w4*4] =
            *(const float4*)(src + (size_t)ch*XSLICE + r*W + f0w4*4);
        if (tid < 256) {
            const int ch1 = f1row / 3, r1 = f1row - 3*ch1;
            *(float4*)&xbuf[0][f1row*128 + f1w4*4] =
                *(const float4*)(src + (size_t)ch1*XSLICE + r1*W + f1w4*4);
        }
    }
    __syncthreads();                 // xbuf[0] + a/b ready

    float sum = 0.f;
    int buf = 0;
    for (int g = 0; g < GROUP; ++g) {
        if (g + 1 < GROUP) {         // stage g+1 into buf^1 (no readers yet)
            const float* src = xrow + (size_t)((g+1)*CPG)*XSLICE;
            const int ch = f0row / 3, r = f0row - 3*ch;
            *(float4*)&xbuf[buf^1][f0row*128 + f0w4*4] =
                *(const float4*)(src + (size_t)ch*XSLICE + r*W + f0w4*4);
            if (tid < 256) {
                const int ch1 = f1row / 3, r1 = f1row - 3*ch1;
                *(float4*)&xbuf[buf^1][f1row*128 + f1w4*4] =
                    *(const float4*)(src + (size_t)ch1*XSLICE + r1*W + f1w4*4);
            }
        }
        if (act) {
            float acc0 = 0.f, acc1 = 0.f;
            #pragma unroll
            for (int p = 0; p < 9; ++p) {
                const int ch = g * 9 + p;
                float s = sp[(size_t)ch * HW] * a[ch] + b[ch];
                float e = __expf(s);
                sum += e;
                const int r = p / 3, cx = p - 3*r;
                const int w = pos + cx;          // <= 127, in-slab
                acc0 += xbuf[buf][((gc*2 + 0)*3 + r)*128 + w] * e;
                acc1 += xbuf[buf][((gc*2 + 1)*3 + r)*128 + w] * e;
            }
            ob[(size_t)(g*CPG + gc*2 + 0) * HW] = acc0;
            ob[(size_t)(g*CPG + gc*2 + 1) * HW] = acc1;
        }
        __syncthreads();             // buf readers done; buf^1 writes visible
        buf ^= 1;
    }
    if (act && gc == 0) sums[(size_t)n * HW + hw] = sum;
}

// ---------------- Bilinear align-corners upsample 126 -> 128 (+ softmax divide) ----
__global__ __launch_bounds__(256) void upsample_kernel(const float* __restrict__ lo,
                                                       const float* __restrict__ sums,
                                                       float* __restrict__ out) {
    const int idx = blockIdx.x * 256 + threadIdx.x;
    const int xi = idx & (W - 1);
    const int yi = (idx >> 7) & (H - 1);
    const int nc = idx >> 14;
    const int n  = nc >> 8;              // C = 256

    const float scale = 125.0f / 127.0f;
    const float sy = yi * scale;
    const float sx = xi * scale;
    int y0 = (int)sy;
    int x0 = (int)sx;
    float wy = sy - (float)y0;
    float wx = sx - (float)x0;
    int y1 = min(y0 + 1, OH - 1);
    int x1 = min(x0 + 1, OW - 1);

    const float* p  = lo + (size_t)nc * HW;
    const float* ps = sums + (size_t)n * HW;
    float v00 = p[y0 * OW + x0] / ps[y0 * OW + x0];
    float v01 = p[y0 * OW + x1] / ps[y0 * OW + x1];
    float v10 = p[y1 * OW + x0] / ps[y1 * OW + x0];
    float v11 = p[y1 * OW + x1] / ps[y1 * OW + x1];
    float top = v00 * (1.f - wx) + v01 * wx;
    float bot = v10 * (1.f - wx) + v11 * wx;
    out[idx] = top * (1.f - wy) + bot * wy;
}

extern "C" void kernel_launch(void* const* d_in, const int* in_sizes, int n_in,
                              void* d_out, int out_size, void* d_ws, size_t ws_size,
                              hipStream_t stream) {
    const float* x      = (const float*)d_in[0];
    const float* conv_w = (const float*)d_in[1];
    const float* gamma  = (const float*)d_in[2];
    const float* beta   = (const float*)d_in[3];
    float* out = (float*)d_out;
    float* ws  = (float*)d_ws;

    // workspace (floats):
    //   sigma : [0, 18289152)
    //   coef  : [18289152, +1024)
    //   outlo : [18290176, +16257024)   -- ALIASED with xh/xl (prep+conv finish first)
    //   sums  : aliased over whT (dead after conv, written by fuse, read by upsample)
    float* sigma = ws;
    float* coef  = ws + 18289152;
    float* outlo = ws + 18290176;
    u16* xhp = (u16*)(ws + 18290176);               // 16777216 u16 = 33.5 MB
    u16* xlp = xhp + (size_t)XTOT;                  // adjacent: xl = xh + XTOT
    u16* whT = xlp + (size_t)XTOT;                  // 663552 u16
    u16* wlT = whT + (size_t)WTOT;                  // adjacent: wl = wh + WTOT
    float* sums = (float*)whT;                      // 63504 floats, fits in w region
    // total ws usage ~143 MB

    split_x_kernel<<<dim3(16, 128, 4), 256, 0, stream>>>(x, xhp, xlp);
    split_w_kernel<<<(9*CO*256)/256, 256, 0, stream>>>(conv_w, whT, wlT);

    conv_mfma_kernel<<<dim3(2, 32, N), 512, 0, stream>>>(xhp, whT, sigma);

    stats_kernel<<<CO, 1024, 0, stream>>>(sigma, gamma, beta, coef);

    fuse_kernel<<<N * OH, 512, 0, stream>>>(x, sigma, coef, outlo, sums);

    upsample_kernel<<<(N * C * H * W) / 256, 256, 0, stream>>>(outlo, sums, out);
}